// Round 9
// baseline (807.714 us; speedup 1.0000x reference)
//
#include <hip/hip_runtime.h>
#include <hip/hip_cooperative_groups.h>
#include <hip/hip_bf16.h>
#include <math.h>

// ---------------------------------------------------------------------------
// MMD-VAE fused pipeline for MI355X (gfx950) -- SINGLE cooperative kernel.
// B=8 S=512 D=1024 DI=4096 DL=64, Nrows = B*S = 4096
// Outputs: recon [4096,1024] f32, latent [4096,64] f32, reg_loss scalar f32
// R9: all 8 launches merged into one hipLaunchCooperativeKernel (256 blocks
// x 512 threads, all co-resident at 1 block/CU).  Phases separated by
// __threadfence() + grid.sync().  Phase math copied from the R8
// harness-verified kernels; only indexing shells adapted.
// ---------------------------------------------------------------------------

namespace cg = cooperative_groups;

typedef __attribute__((ext_vector_type(8))) short short8;    // 8 bf16 = 4 VGPR
typedef __attribute__((ext_vector_type(4))) float float4a;   // MFMA accum
typedef __attribute__((ext_vector_type(4))) unsigned short us4;

__device__ inline ushort bf16r(float x) {
    union { float f; unsigned u; } c; c.f = x;
    unsigned r = (c.u + 0x7fffu + ((c.u >> 16) & 1u)) >> 16;
    return (ushort)r;
}

// async global->LDS, 16B per lane, LDS dst = wave-uniform base + lane*16
__device__ inline void gld_lds16(const void* g, void* l) {
    __builtin_amdgcn_global_load_lds(
        (const __attribute__((address_space(1))) void*)g,
        (__attribute__((address_space(3))) void*)l, 16, 0, 0);
}

template <int N> __device__ inline void wait_vmcnt() {
    if constexpr (N == 0) asm volatile("s_waitcnt vmcnt(0)" ::: "memory");
}

template <int N> __device__ inline void wait_lgkmcnt() {
    if constexpr (N == 0) asm volatile("s_waitcnt lgkmcnt(0)" ::: "memory");
    else if constexpr (N == 12) asm volatile("s_waitcnt lgkmcnt(12)" ::: "memory");
}

// tanh-form gelu via sigmoid identity: 0.5v(1+tanh(z)) = v*sigmoid(2z).
__device__ inline float fast_gelu(float v) {
    float v2 = v * v;
    float u = v * __builtin_fmaf(0.07135481627f, v2, 1.5957691216f);
    u = fminf(u, 30.0f);
    float e = __expf(u);
    return v * e * __builtin_amdgcn_rcpf(e + 1.0f);
}

// ---------------------------------------------------------------------------
__global__ __launch_bounds__(512, 2) void k_mega(
        const float* __restrict__ hidden, const float* __restrict__ tsamp,
        const float* __restrict__ ew1, const float* __restrict__ eb1,
        const float* __restrict__ ew2, const float* __restrict__ eb2,
        const float* __restrict__ elng, const float* __restrict__ elnb,
        const float* __restrict__ dw1, const float* __restrict__ db1,
        const float* __restrict__ dw2, const float* __restrict__ db2,
        const float* __restrict__ dlng, const float* __restrict__ dlnb,
        float* __restrict__ recon, float* __restrict__ latent_f,
        float* __restrict__ regout,
        ushort* __restrict__ A1bf, ushort* __restrict__ W1t,
        float* __restrict__ part, float* __restrict__ h4p0,
        ushort* __restrict__ H1bf, ushort* __restrict__ W4t,
        ushort* __restrict__ W2t, ushort* __restrict__ W3t,
        ushort* __restrict__ Lbf, float* __restrict__ sq_t,
        float* __restrict__ sq_l, float* __restrict__ acc3,
        ushort* __restrict__ Tbf) {
    __shared__ char smem_u[131072];
    cg::grid_group grid = cg::this_grid();

    const int bid = blockIdx.x;
    const int tid = threadIdx.x;
    const int wave = tid >> 6, lane = tid & 63;
    const int htid = tid & 255, half = tid >> 8;  // half-block adapters
    const int lrow = lane & 15, lq = lane >> 4;
    const int srow8 = lane >> 3, sk8 = lane & 7;

    // ================= P0: pre (cvt + tsamp-sq + transposes + zero) =======
    {
        if (bid == 0 && tid < 32) acc3[tid] = 0.0f;   // accums + ticket ctr
        // hidden f32 -> bf16: 4M floats, flat, 8 float4/thread
#pragma unroll
        for (int it = 0; it < 8; ++it) {
            int i4 = it * 131072 + bid * 512 + tid;
            float4 v = ((const float4*)hidden)[i4];
            us4 o = {bf16r(v.x), bf16r(v.y), bf16r(v.z), bf16r(v.w)};
            ((us4*)A1bf)[i4] = o;
        }
        // tsamp cvt + row sqnorms: wave gw<1024 handles rows gw*4+q
        {
            int gw = bid * 8 + wave;
            if (gw < 1024) {
                int row = gw * 4 + (lane >> 4);
                int i = row * 64 + (lane & 15) * 4;
                float4 v = *(const float4*)(tsamp + i);
                us4 o = {bf16r(v.x), bf16r(v.y), bf16r(v.z), bf16r(v.w)};
                *(us4*)(Tbf + i) = o;
                float s = v.x * v.x + v.y * v.y + v.z * v.z + v.w * v.w;
#pragma unroll
                for (int off = 8; off; off >>= 1) s += __shfl_xor(s, off);
                if ((lane & 15) == 0) sq_t[row] = s;
            }
        }
        // transposes: 4352 vtiles of 64rows x 32cols, half-block, 9 iters
        float (*tT)[65] = (float(*)[65])(smem_u + half * 8320);
        int tx = htid & 31, ty = htid >> 5;   // ty 0..7
        for (int it = 0; it < 9; ++it) {
            int vt = (bid + it * 256) * 2 + half;
            bool act = vt < 4352;
            const float* in = nullptr; ushort* out = nullptr; int R = 1, C = 32;
            int lb = vt;
            if (act) {
                if (lb < 2048)      { in = ew1; out = W1t; R = 1024; C = 4096; }
                else if (lb < 2176) { in = ew2; out = W2t; R = 4096; C = 64;   lb -= 2048; }
                else if (lb < 2304) { in = dw1; out = W3t; R = 64;   C = 4096; lb -= 2176; }
                else                { in = dw2; out = W4t; R = 4096; C = 1024; lb -= 2304; }
            }
            int bx = act ? (lb % (C / 32)) * 32 : 0;
            int by = act ? (lb / (C / 32)) * 64 : 0;
            if (act) {
#pragma unroll
                for (int i = 0; i < 64; i += 8)
                    tT[tx][i + ty] = in[(size_t)(by + i + ty) * C + (bx + tx)];
            }
            __syncthreads();
            if (act) {
#pragma unroll
                for (int i = 0; i < 32; i += 8) {
                    int c = i + ty;
                    ushort2 o;
                    o.x = bf16r(tT[c][2 * tx]);
                    o.y = bf16r(tT[c][2 * tx + 1]);
                    *(ushort2*)(&out[(size_t)(bx + c) * R + by + 2 * tx]) = o;
                }
            }
            __syncthreads();
        }
    }
    __threadfence();
    grid.sync();

    // ================= P1: fused GEMM1+GEMM2 (R8 k_gemm1f body) ============
    {
        constexpr int AI = 4, BI = 4, MT = 8, NT = 4;
        constexpr int WM = 128, CX = 4, CY = 8;
        ushort* smem = (ushort*)smem_u;
        const int wm = wave / 4, wn = wave % 4;
        // chunked XCD swizzle (grid 16x16 flat)
        const int lin = bid;
        const int cpx = 256 >> 3;
        const int swz = (lin & 7) * cpx + (lin >> 3);
        const int chunk = swz / (CX * CY);
        const int lcl   = swz % (CX * CY);
        const int ncx   = 16 / CX;
        const int bx = (chunk % ncx) * CX + (lcl % CX);
        const int by = (chunk / ncx) * CY + (lcl / CX);
        const int m0 = by * 256, n0 = bx * 256;
        const int K = 1024, nT = 16;

        const int crow = tid >> 3;
        const int ck8  = (tid & 7) ^ (crow & 7);
        const ushort* pAbase = A1bf + (size_t)(m0 + crow) * K + ck8 * 8;
        const ushort* pBbase = W1t  + (size_t)(n0 + crow) * K + ck8 * 8;

        const int a0  = (wm * WM + lrow) * 64;
        const int b0  = (wn * 64 + lrow) * 64;
        const int sw0 = ((lq) ^ (lrow & 7)) * 8;
        const int sw1 = ((4 + lq) ^ (lrow & 7)) * 8;

        float4a acc[MT][NT];
#pragma unroll
        for (int mt = 0; mt < MT; ++mt)
#pragma unroll
            for (int nt = 0; nt < NT; ++nt)
                acc[mt][nt] = (float4a){0.f, 0.f, 0.f, 0.f};

#pragma unroll
        for (int j = 0; j < AI; ++j)
            gld_lds16(pAbase + (size_t)j * 64 * K, &smem[j * 4096 + wave * 512]);
#pragma unroll
        for (int j = 0; j < BI; ++j)
            gld_lds16(pBbase + (size_t)j * 64 * K,
                      &smem[32768 + j * 4096 + wave * 512]);
        wait_vmcnt<0>();
        __builtin_amdgcn_s_barrier();
        __builtin_amdgcn_sched_barrier(0);

        for (int t = 0; t < nT; ++t) {
            const int d = t & 1;
            const bool pf1 = (t + 1 < nT);
            const size_t koff1 = (size_t)(t + 1) * 64;
            const ushort* sAd = &smem[d * 16384];
            const ushort* sBd = &smem[32768 + d * 16384];

            short8 af0[MT], bfr0[NT], af1[MT], bfr1[NT];
#pragma unroll
            for (int mt = 0; mt < MT; ++mt)
                af0[mt] = *(const short8*)(&sAd[a0 + mt * 1024 + sw0]);
#pragma unroll
            for (int nt = 0; nt < NT; ++nt)
                bfr0[nt] = *(const short8*)(&sBd[b0 + nt * 1024 + sw0]);
            __builtin_amdgcn_sched_barrier(0);
#pragma unroll
            for (int mt = 0; mt < MT; ++mt)
                af1[mt] = *(const short8*)(&sAd[a0 + mt * 1024 + sw1]);
#pragma unroll
            for (int nt = 0; nt < NT; ++nt)
                bfr1[nt] = *(const short8*)(&sBd[b0 + nt * 1024 + sw1]);
            if (pf1) {
#pragma unroll
                for (int j = 0; j < AI; ++j)
                    gld_lds16(pAbase + (size_t)j * 64 * K + koff1,
                              &smem[(d ^ 1) * 16384 + j * 4096 + wave * 512]);
#pragma unroll
                for (int j = 0; j < BI; ++j)
                    gld_lds16(pBbase + (size_t)j * 64 * K + koff1,
                              &smem[32768 + (d ^ 1) * 16384 + j * 4096 + wave * 512]);
            }
            wait_lgkmcnt<12>();
            __builtin_amdgcn_sched_barrier(0);
            __builtin_amdgcn_s_setprio(1);
#pragma unroll
            for (int mt = 0; mt < MT; ++mt)
#pragma unroll
                for (int nt = 0; nt < NT; ++nt)
                    acc[mt][nt] = __builtin_amdgcn_mfma_f32_16x16x32_bf16(
                        af0[mt], bfr0[nt], acc[mt][nt], 0, 0, 0);
            __builtin_amdgcn_s_setprio(0);
            wait_lgkmcnt<0>();
            __builtin_amdgcn_sched_barrier(0);
            __builtin_amdgcn_s_setprio(1);
#pragma unroll
            for (int mt = 0; mt < MT; ++mt)
#pragma unroll
                for (int nt = 0; nt < NT; ++nt)
                    acc[mt][nt] = __builtin_amdgcn_mfma_f32_16x16x32_bf16(
                        af1[mt], bfr1[nt], acc[mt][nt], 0, 0, 0);
            __builtin_amdgcn_s_setprio(0);
            if (pf1) {
                wait_vmcnt<0>();
                __builtin_amdgcn_s_barrier();
                __builtin_amdgcn_sched_barrier(0);
            }
        }

        // fused epilogue: gelu -> sH (LDS), then P = sH x W2slice^T
        __syncthreads();
#pragma unroll
        for (int mt = 0; mt < MT; ++mt)
#pragma unroll
            for (int nt = 0; nt < NT; ++nt) {
                const int c = wn * 64 + nt * 16 + lrow;
                const float bv = eb1[n0 + c];
                const int s = c >> 3, cl = c & 7;
#pragma unroll
                for (int r_ = 0; r_ < 4; ++r_) {
                    const int r = wm * WM + mt * 16 + lq * 4 + r_;
                    const int sz = (s & 24) | ((s & 7) ^ (r & 7));
                    smem[r * 256 + sz * 8 + cl] =
                        bf16r(fast_gelu(acc[mt][nt][r_] + bv));
                }
            }
        __syncthreads();

        float4a pacc[2][4];
#pragma unroll
        for (int m2 = 0; m2 < 2; ++m2)
#pragma unroll
            for (int n2 = 0; n2 < 4; ++n2)
                pacc[m2][n2] = (float4a){0.f, 0.f, 0.f, 0.f};

        const ushort* gW2 = W2t + n0;
#pragma unroll
        for (int kk = 0; kk < 8; ++kk) {
            short8 af2[2], bf2[4];
#pragma unroll
            for (int m2 = 0; m2 < 2; ++m2) {
                const int r2 = wave * 32 + m2 * 16 + lrow;
                const int s2 = kk * 4 + lq;
                const int sz2 = (s2 & 24) | ((s2 & 7) ^ (r2 & 7));
                af2[m2] = *(const short8*)(&smem[r2 * 256 + sz2 * 8]);
            }
#pragma unroll
            for (int n2 = 0; n2 < 4; ++n2) {
                const int l = n2 * 16 + lrow;
                bf2[n2] = *(const short8*)(&gW2[(size_t)l * 4096 + kk * 32 + lq * 8]);
            }
#pragma unroll
            for (int m2 = 0; m2 < 2; ++m2)
#pragma unroll
                for (int n2 = 0; n2 < 4; ++n2)
                    pacc[m2][n2] = __builtin_amdgcn_mfma_f32_16x16x32_bf16(
                        af2[m2], bf2[n2], pacc[m2][n2], 0, 0, 0);
        }

        float* pz = part + (size_t)bx * 4096 * 64;
#pragma unroll
        for (int m2 = 0; m2 < 2; ++m2)
#pragma unroll
            for (int n2 = 0; n2 < 4; ++n2) {
                const int lat = n2 * 16 + lrow;
#pragma unroll
                for (int r_ = 0; r_ < 4; ++r_) {
                    const int row = m0 + wave * 32 + m2 * 16 + lq * 4 + r_;
                    pz[(size_t)row * 64 + lat] = pacc[m2][n2][r_];
                }
            }
    }
    __threadfence();
    grid.sync();

    // ================= P2: ln64 (split-16 reduce + LN + sq_l) ==============
    {
        int gw = bid * 8 + wave;   // 0..2047
#pragma unroll
        for (int rr = 0; rr < 2; ++rr) {
            int row = gw + rr * 2048;
            float x = eb2[lane];
            for (int s = 0; s < 16; ++s)
                x += part[(size_t)s * 4096 * 64 + row * 64 + lane];
            float s = x;
#pragma unroll
            for (int off = 32; off; off >>= 1) s += __shfl_xor(s, off);
            float mu = s * (1.0f / 64.0f);
            float dxx = x - mu;
            float v = dxx * dxx;
#pragma unroll
            for (int off = 32; off; off >>= 1) v += __shfl_xor(v, off);
            float rs = rsqrtf(v * (1.0f / 64.0f) + 1e-9f);
            float y = dxx * rs * elng[lane] + elnb[lane];
            latent_f[row * 64 + lane] = y;
            Lbf[row * 64 + lane] = bf16r(y);
            float q = y * y;
#pragma unroll
            for (int off = 32; off; off >>= 1) q += __shfl_xor(q, off);
            if (lane == 0) sq_l[row] = q;
        }
    }
    __threadfence();
    grid.sync();

    // ================= P3: GEMM3 (K=64, half-block, 4 iters) ===============
    {
        ushort* sA3 = (ushort*)(smem_u + half * 24576);
        ushort* sB3 = sA3 + 8192;
        const int w4 = htid >> 6, hl = htid & 63;
        const int hlrow = hl & 15, hlq = hl >> 4;
        const int hsr8 = hl >> 3, hsk8 = hl & 7;
        for (int it = 0; it < 4; ++it) {
            int vt = (bid * 2 + half) + it * 512;   // 0..2047
            int bx3 = vt & 63, by3 = vt >> 6;
            int m0 = by3 * 128, n0 = bx3 * 64;
#pragma unroll
            for (int j = 0; j < 4; ++j) {
                int c = w4 * 4 + j;
                int r = c * 8 + hsr8;
                gld_lds16(&Lbf[(size_t)(m0 + r) * 64 + ((hsk8 ^ (r & 7)) * 8)],
                          &sA3[c * 512]);
            }
#pragma unroll
            for (int j = 0; j < 2; ++j) {
                int c = w4 * 2 + j;
                int r = c * 8 + hsr8;
                gld_lds16(&W3t[(size_t)(n0 + r) * 64 + ((hsk8 ^ (r & 7)) * 8)],
                          &sB3[c * 512]);
            }
            __syncthreads();
            float4a a3[2][4];
#pragma unroll
            for (int mt = 0; mt < 2; ++mt)
#pragma unroll
                for (int nt = 0; nt < 4; ++nt)
                    a3[mt][nt] = (float4a){0.f, 0.f, 0.f, 0.f};
#pragma unroll
            for (int h = 0; h < 2; ++h) {
                short8 af[2], bfr[4];
#pragma unroll
                for (int mt = 0; mt < 2; ++mt) {
                    int r = w4 * 32 + mt * 16 + hlrow;
                    af[mt] = *(short8*)(&sA3[r * 64 + (((h * 4 + hlq) ^ (r & 7)) * 8)]);
                }
#pragma unroll
                for (int nt = 0; nt < 4; ++nt) {
                    int r = nt * 16 + hlrow;
                    bfr[nt] = *(short8*)(&sB3[r * 64 + (((h * 4 + hlq) ^ (r & 7)) * 8)]);
                }
#pragma unroll
                for (int mt = 0; mt < 2; ++mt)
#pragma unroll
                    for (int nt = 0; nt < 4; ++nt)
                        a3[mt][nt] = __builtin_amdgcn_mfma_f32_16x16x32_bf16(
                            af[mt], bfr[nt], a3[mt][nt], 0, 0, 0);
            }
            __syncthreads();
#pragma unroll
            for (int mt = 0; mt < 2; ++mt)
#pragma unroll
                for (int nt = 0; nt < 4; ++nt) {
                    int col = n0 + nt * 16 + hlrow;
                    float bv = db1[col];
#pragma unroll
                    for (int r_ = 0; r_ < 4; ++r_) {
                        int row = m0 + w4 * 32 + mt * 16 + hlq * 4 + r_;
                        H1bf[(size_t)row * 4096 + col] =
                            bf16r(fast_gelu(a3[mt][nt][r_] + bv));
                    }
                }
        }
    }
    __threadfence();
    grid.sync();

    // ================= P4: GEMM4 min-barrier (256x128, split-K=2) ==========
    {
        constexpr int AI = 4, BI = 2, MT = 4, NT = 4, WM = 64;
        constexpr int CX = 8, CY = 4;
        ushort* sA4 = (ushort*)smem_u;                 // [2][16384]
        ushort* sB4 = (ushort*)(smem_u + 65536);       // [2][8192]
        const int wm = wave / 2, wn = wave % 2;
        const int gx = 8, gy = 16;
        const int lin = bid;
        const int cpx = 256 >> 3;
        const int swz = (lin & 7) * cpx + (lin >> 3);
        const int nz  = gx * gy;
        const int zz  = swz / nz;
        const int rr  = swz % nz;
        const int chunk = rr / (CX * CY);
        const int lcl   = rr % (CX * CY);
        const int ncx   = gx / CX;
        const int bx = (chunk % ncx) * CX + (lcl % CX);
        const int by = (chunk / ncx) * CY + (lcl / CX);
        const int m0 = by * 256, n0 = bx * 128;
        const int K = 4096, KC = 2048, nT = 32;
        const int kbeg = zz * KC;

        const int crow = tid >> 3;
        const int ck8  = (tid & 7) ^ (crow & 7);
        const ushort* pAbase = H1bf + (size_t)(m0 + crow) * K + kbeg + ck8 * 8;
        const ushort* pBbase = W4t  + (size_t)(n0 + crow) * K + kbeg + ck8 * 8;

        const int a0  = (wm * WM + lrow) * 64;
        const int b0  = (wn * 64 + lrow) * 64;
        const int sw0 = ((lq) ^ (lrow & 7)) * 8;
        const int sw1 = ((4 + lq) ^ (lrow & 7)) * 8;

        float4a acc[MT][NT];
#pragma unroll
        for (int mt = 0; mt < MT; ++mt)
#pragma unroll
            for (int nt = 0; nt < NT; ++nt)
                acc[mt][nt] = (float4a){0.f, 0.f, 0.f, 0.f};

#pragma unroll
        for (int j = 0; j < AI; ++j)
            gld_lds16(pAbase + (size_t)j * 64 * K, &sA4[j * 4096 + wave * 512]);
#pragma unroll
        for (int j = 0; j < BI; ++j)
            gld_lds16(pBbase + (size_t)j * 64 * K, &sB4[j * 4096 + wave * 512]);
        wait_vmcnt<0>();
        __builtin_amdgcn_s_barrier();
        __builtin_amdgcn_sched_barrier(0);

        for (int t = 0; t < nT; ++t) {
            const int d = t & 1;
            const bool pf1 = (t + 1 < nT);
            const size_t koff1 = (size_t)(t + 1) * 64;
            const ushort* sAd = &sA4[d * 16384];
            const ushort* sBd = &sB4[d * 8192];

            short8 af0[MT], bfr0[NT], af1[MT], bfr1[NT];
#pragma unroll
            for (int mt = 0; mt < MT; ++mt)
                af0[mt] = *(const short8*)(&sAd[a0 + mt * 1024 + sw0]);
#pragma unroll
            for (int nt = 0; nt < NT; ++nt)
                bfr0[nt] = *(const short8*)(&sBd[b0 + nt * 1024 + sw0]);
            __builtin_amdgcn_sched_barrier(0);
#pragma unroll
            for (int mt = 0; mt < MT; ++mt)
                af1[mt] = *(const short8*)(&sAd[a0 + mt * 1024 + sw1]);
#pragma unroll
            for (int nt = 0; nt < NT; ++nt)
                bfr1[nt] = *(const short8*)(&sBd[b0 + nt * 1024 + sw1]);
            if (pf1) {
#pragma unroll
                for (int j = 0; j < AI; ++j)
                    gld_lds16(pAbase + (size_t)j * 64 * K + koff1,
                              &sA4[(d ^ 1) * 16384 + j * 4096 + wave * 512]);
#pragma unroll
                for (int j = 0; j < BI; ++j)
                    gld_lds16(pBbase + (size_t)j * 64 * K + koff1,
                              &sB4[(d ^ 1) * 8192 + j * 4096 + wave * 512]);
            }
            wait_lgkmcnt<12>();   // af0(4)+bfr0(4) done; 8 outstanding
            __builtin_amdgcn_sched_barrier(0);
            __builtin_amdgcn_s_setprio(1);
#pragma unroll
            for (int mt = 0; mt < MT; ++mt)
#pragma unroll
                for (int nt = 0; nt < NT; ++nt)
                    acc[mt][nt] = __builtin_amdgcn_mfma_f32_16x16x32_bf16(
                        af0[mt], bfr0[nt], acc[mt][nt], 0, 0, 0);
            __builtin_amdgcn_s_setprio(0);
            wait_lgkmcnt<0>();
            __builtin_amdgcn_sched_barrier(0);
            __builtin_amdgcn_s_setprio(1);
#pragma unroll
            for (int mt = 0; mt < MT; ++mt)
#pragma unroll
                for (int nt = 0; nt < NT; ++nt)
                    acc[mt][nt] = __builtin_amdgcn_mfma_f32_16x16x32_bf16(
                        af1[mt], bfr1[nt], acc[mt][nt], 0, 0, 0);
            __builtin_amdgcn_s_setprio(0);
            if (pf1) {
                wait_vmcnt<0>();
                __builtin_amdgcn_s_barrier();
                __builtin_amdgcn_sched_barrier(0);
            }
        }

        float* dstp = zz ? recon : h4p0;
#pragma unroll
        for (int mt = 0; mt < MT; ++mt)
#pragma unroll
            for (int nt = 0; nt < NT; ++nt) {
                const int col = n0 + wn * 64 + nt * 16 + lrow;
#pragma unroll
                for (int r_ = 0; r_ < 4; ++r_) {
                    const int row = m0 + wm * WM + mt * 16 + lq * 4 + r_;
                    dstp[(size_t)row * 1024 + col] = acc[mt][nt][r_];
                }
            }
    }
    __threadfence();
    grid.sync();

    // ================= P5: ln1024 (half-block, 8 iters) ====================
    {
        float* red5 = (float*)smem_u + half * 4;
        for (int it = 0; it < 8; ++it) {
            int row = (bid * 2 + half) + it * 512;
            const float4 v0 = *(const float4*)(h4p0 + (size_t)row * 1024 + htid * 4);
            const float4 v1 = *(const float4*)(recon + (size_t)row * 1024 + htid * 4);
            const float4 bb = *(const float4*)(db2 + htid * 4);
            float4 v;
            v.x = v0.x + v1.x + bb.x;
            v.y = v0.y + v1.y + bb.y;
            v.z = v0.z + v1.z + bb.z;
            v.w = v0.w + v1.w + bb.w;
            float s = v.x + v.y + v.z + v.w;
#pragma unroll
            for (int off = 32; off; off >>= 1) s += __shfl_xor(s, off);
            if ((htid & 63) == 0) red5[htid >> 6] = s;
            __syncthreads();
            float mu = (red5[0] + red5[1] + red5[2] + red5[3]) * (1.0f / 1024.0f);
            float dx = v.x - mu, dy = v.y - mu, dz = v.z - mu, dw = v.w - mu;
            float q = dx * dx + dy * dy + dz * dz + dw * dw;
#pragma unroll
            for (int off = 32; off; off >>= 1) q += __shfl_xor(q, off);
            __syncthreads();
            if ((htid & 63) == 0) red5[htid >> 6] = q;
            __syncthreads();
            float rs = rsqrtf((red5[0] + red5[1] + red5[2] + red5[3]) *
                              (1.0f / 1024.0f) + 1e-9f);
            const float4 gv = *(const float4*)(dlng + htid * 4);
            const float4 bv = *(const float4*)(dlnb + htid * 4);
            float4 o;
            o.x = dx * rs * gv.x + bv.x;
            o.y = dy * rs * gv.y + bv.y;
            o.z = dz * rs * gv.z + bv.z;
            o.w = dw * rs * gv.w + bv.w;
            *(float4*)(recon + (size_t)row * 1024 + htid * 4) = o;
            __syncthreads();
        }
    }
    __threadfence();
    grid.sync();

    // ================= P6: MMD grams (half-block, 5 iters) + finalize ======
    {
        ushort* sX = (ushort*)(smem_u + half * 32768);
        ushort* sY = sX + 8192;
        float* red6 = (float*)(smem_u + 65536) + half * 4;
        const int w4 = htid >> 6, hl = htid & 63;
        const int hlrow = hl & 15, hlq = hl >> 4;
        const int hsr8 = hl >> 3, hsk8 = hl & 7;
        const int wmg = w4 >> 1, wng = w4 & 1;

        for (int it = 0; it < 5; ++it) {
            int id = (bid * 2 + half) + it * 512;
            bool act = id < 2080;
            int pair = 0, tbx = 0, tby = 0; float w = 1.0f;
            const ushort *Xb = Tbf, *Yb = Tbf;
            const float *sqX = sq_t, *sqY = sq_t;
            if (act) {
                if (id < 1056) {
                    pair = (id < 528) ? 0 : 1;
                    int t = (pair == 0) ? id : id - 528;
                    int r = (int)((sqrtf(8.0f * t + 1.0f) - 1.0f) * 0.5f);
                    while ((r + 1) * (r + 2) / 2 <= t) ++r;
                    while (r * (r + 1) / 2 > t) --r;
                    tby = r; tbx = t - r * (r + 1) / 2;
                    w = (tbx == tby) ? 1.0f : 2.0f;
                } else {
                    pair = 2; int t = id - 1056;
                    tbx = t & 31; tby = t >> 5; w = 1.0f;
                }
                Xb = (pair == 1) ? Lbf : Tbf;
                Yb = (pair == 0) ? Tbf : Lbf;
                sqX = (pair == 1) ? sq_l : sq_t;
                sqY = (pair == 0) ? sq_t : sq_l;
            }
            const int bx = tbx * 128, by = tby * 128;
            if (act) {
#pragma unroll
                for (int j = 0; j < 4; ++j) {
                    int c = w4 * 4 + j;
                    int r = c * 8 + hsr8;
                    int kc = (hsk8 ^ (r & 7)) * 8;
                    gld_lds16(&Xb[(size_t)(bx + r) * 64 + kc], &sX[c * 512]);
                    gld_lds16(&Yb[(size_t)(by + r) * 64 + kc], &sY[c * 512]);
                }
            }
            __syncthreads();
            float s = 0.f;
            if (act) {
                float4a ag[4][4];
#pragma unroll
                for (int mt = 0; mt < 4; ++mt)
#pragma unroll
                    for (int nt = 0; nt < 4; ++nt)
                        ag[mt][nt] = (float4a){0.f, 0.f, 0.f, 0.f};
#pragma unroll
                for (int h = 0; h < 2; ++h) {
                    short8 xf[4], yf[4];
#pragma unroll
                    for (int mt = 0; mt < 4; ++mt) {
                        int rx = wmg * 64 + mt * 16 + hlrow;
                        xf[mt] = *(short8*)(&sX[rx * 64 + (((h * 4 + hlq) ^ (rx & 7)) * 8)]);
                    }
#pragma unroll
                    for (int nt = 0; nt < 4; ++nt) {
                        int ry = wng * 64 + nt * 16 + hlrow;
                        yf[nt] = *(short8*)(&sY[ry * 64 + (((h * 4 + hlq) ^ (ry & 7)) * 8)]);
                    }
#pragma unroll
                    for (int mt = 0; mt < 4; ++mt)
#pragma unroll
                        for (int nt = 0; nt < 4; ++nt)
                            ag[mt][nt] = __builtin_amdgcn_mfma_f32_16x16x32_bf16(
                                xf[mt], yf[nt], ag[mt][nt], 0, 0, 0);
                }
                float sy[4];
#pragma unroll
                for (int nt = 0; nt < 4; ++nt)
                    sy[nt] = sqY[by + wng * 64 + nt * 16 + hlrow];
#pragma unroll
                for (int mt = 0; mt < 4; ++mt)
#pragma unroll
                    for (int r = 0; r < 4; ++r) {
                        float sx = sqX[bx + wmg * 64 + mt * 16 + hlq * 4 + r];
#pragma unroll
                        for (int nt = 0; nt < 4; ++nt)
                            s += __expf((2.0f * ag[mt][nt][r] - sx - sy[nt]) *
                                        (1.0f / 4096.0f));
                    }
                s *= w;
#pragma unroll
                for (int off = 32; off; off >>= 1) s += __shfl_xor(s, off);
                if (hl == 0) red6[w4] = s;
            }
            __syncthreads();
            if (act && htid == 0) {
                atomicAdd(acc3 + pair * 8, red6[0] + red6[1] + red6[2] + red6[3]);
                __threadfence();
                unsigned prev = atomicAdd((unsigned*)(acc3 + 24), 1u);
                if (prev == 2079) {
                    float a0 = atomicAdd(acc3 + 0, 0.0f);
                    float a1 = atomicAdd(acc3 + 8, 0.0f);
                    float a2 = atomicAdd(acc3 + 16, 0.0f);
                    regout[0] = (a0 + a1 - 2.0f * a2) *
                                (64.0f / (4096.0f * 4096.0f));
                }
            }
            __syncthreads();
        }
    }
}

// ---------------------------------------------------------------------------
extern "C" void kernel_launch(void* const* d_in, const int* in_sizes, int n_in,
                              void* d_out, int out_size, void* d_ws, size_t ws_size,
                              hipStream_t stream) {
    const float* hidden   = (const float*)d_in[0];
    const float* tsamp    = (const float*)d_in[1];
    const float* enc_w1   = (const float*)d_in[2];
    const float* enc_b1   = (const float*)d_in[3];
    const float* enc_w2   = (const float*)d_in[4];
    const float* enc_b2   = (const float*)d_in[5];
    const float* enc_ln_g = (const float*)d_in[6];
    const float* enc_ln_b = (const float*)d_in[7];
    const float* dec_w1   = (const float*)d_in[8];
    const float* dec_b1   = (const float*)d_in[9];
    const float* dec_w2   = (const float*)d_in[10];
    const float* dec_b2   = (const float*)d_in[11];
    const float* dec_ln_g = (const float*)d_in[12];
    const float* dec_ln_b = (const float*)d_in[13];

    float* out      = (float*)d_out;
    float* recon    = out;                 // 4096*1024
    float* latent_f = out + 4194304;       // 4096*64
    float* reg      = out + 4456448;       // scalar

    char* ws = (char*)d_ws;
    const size_t MB = 1024 * 1024;
    ushort* A1bf = (ushort*)(ws + 0);                 // 8MB  (P0 W, P1 R)
    ushort* W1t  = (ushort*)(ws + 8 * MB);            // 8MB  (P0 W, P1 R)
    float*  h4p0 = (float*)(ws + 0);                  // 16MB (P4 W, P5 R)
    float*  part = (float*)(ws + 16 * MB);            // 16MB (P1 W, P2 R)
    ushort* H1bf = (ushort*)(ws + 16 * MB);           // 32MB (P3 W, P4 R)
    ushort* W4t  = (ushort*)(ws + 48 * MB);           // 8MB
    ushort* W2t  = (ushort*)(ws + 56 * MB);           // 512K
    ushort* W3t  = (ushort*)(ws + 56 * MB + 512 * 1024); // 512K
    ushort* Lbf  = (ushort*)(ws + 57 * MB);           // 512K
    float*  sq_t = (float*)(ws + 59 * MB);            // 16KB
    float*  sq_l = (float*)(ws + 59 * MB + 16384);    // 16KB
    float*  acc3 = (float*)(ws + 59 * MB + 32768);    // accums + ticket ctr
    ushort* Tbf  = (ushort*)(ws + 59 * MB + 65536);   // 512K

    void* args[] = {
        (void*)&hidden, (void*)&tsamp,
        (void*)&enc_w1, (void*)&enc_b1, (void*)&enc_w2, (void*)&enc_b2,
        (void*)&enc_ln_g, (void*)&enc_ln_b,
        (void*)&dec_w1, (void*)&dec_b1, (void*)&dec_w2, (void*)&dec_b2,
        (void*)&dec_ln_g, (void*)&dec_ln_b,
        (void*)&recon, (void*)&latent_f, (void*)&reg,
        (void*)&A1bf, (void*)&W1t, (void*)&part, (void*)&h4p0,
        (void*)&H1bf, (void*)&W4t, (void*)&W2t, (void*)&W3t,
        (void*)&Lbf, (void*)&sq_t, (void*)&sq_l, (void*)&acc3, (void*)&Tbf
    };
    hipLaunchCooperativeKernel((void*)k_mega, dim3(256), dim3(512),
                               args, 0, stream);
}

// Round 10
// 282.711 us; speedup vs baseline: 2.8570x; 2.8570x over previous
//
#include <hip/hip_runtime.h>
#include <hip/hip_bf16.h>
#include <math.h>

// ---------------------------------------------------------------------------
// MMD-VAE fused pipeline for MI355X (gfx950)
// B=8 S=512 D=1024 DI=4096 DL=64, Nrows = B*S = 4096
// Outputs: recon [4096,1024] f32, latent [4096,64] f32, reg_loss scalar f32
// R10: R8 base (best: 260.6us) + (a) GEMM4 3-stage pipeline with counted
// vmcnt (never drains to 0 mid-loop), (b) finalize merged into gram via
// ticket counter (one launch fewer).  R9 mega-kernel refuted and reverted.
// ---------------------------------------------------------------------------

typedef __attribute__((ext_vector_type(8))) short short8;    // 8 bf16 = 4 VGPR
typedef __attribute__((ext_vector_type(4))) float float4a;   // MFMA accum
typedef __attribute__((ext_vector_type(4))) unsigned short us4;

__device__ inline ushort bf16r(float x) {
    union { float f; unsigned u; } c; c.f = x;
    unsigned r = (c.u + 0x7fffu + ((c.u >> 16) & 1u)) >> 16;
    return (ushort)r;
}

// async global->LDS, 16B per lane, LDS dst = wave-uniform base + lane*16
__device__ inline void gld_lds16(const void* g, void* l) {
    __builtin_amdgcn_global_load_lds(
        (const __attribute__((address_space(1))) void*)g,
        (__attribute__((address_space(3))) void*)l, 16, 0, 0);
}

template <int N> __device__ inline void wait_vmcnt() {
    if constexpr (N == 0) asm volatile("s_waitcnt vmcnt(0)" ::: "memory");
    else if constexpr (N == 4) asm volatile("s_waitcnt vmcnt(4)" ::: "memory");
    else if constexpr (N == 6) asm volatile("s_waitcnt vmcnt(6)" ::: "memory");
}

template <int N> __device__ inline void wait_lgkmcnt() {
    if constexpr (N == 0) asm volatile("s_waitcnt lgkmcnt(0)" ::: "memory");
    else if constexpr (N == 8) asm volatile("s_waitcnt lgkmcnt(8)" ::: "memory");
    else if constexpr (N == 12) asm volatile("s_waitcnt lgkmcnt(12)" ::: "memory");
}

// tanh-form gelu via sigmoid identity: 0.5v(1+tanh(z)) = v*sigmoid(2z).
// 2z = 1.5957691*v + 0.07135482*v^3.  |err| <~1e-3 (<< bf16 rounding here).
__device__ inline float fast_gelu(float v) {
    float v2 = v * v;
    float u = v * __builtin_fmaf(0.07135481627f, v2, 1.5957691216f);
    u = fminf(u, 30.0f);                       // overflow guard
    float e = __expf(u);
    return v * e * __builtin_amdgcn_rcpf(e + 1.0f);
}

// ---------------- fused pre-pass: conversions + transposes + zeroing -------
__global__ __launch_bounds__(256) void k_pre(
        const float* __restrict__ hidden, ushort* __restrict__ A1bf,
        const float* __restrict__ tsamp, ushort* __restrict__ Tbf,
        float* __restrict__ sq_t, float* __restrict__ acc,
        const float* __restrict__ i0, ushort* __restrict__ o0,
        const float* __restrict__ i1, ushort* __restrict__ o1,
        const float* __restrict__ i2, ushort* __restrict__ o2,
        const float* __restrict__ i3, ushort* __restrict__ o3) {
    int b = blockIdx.x, tid = threadIdx.x;
    if (b == 0 && tid < 32) acc[tid] = 0.0f;   // 3 accumulators + ticket ctr
    if (b < 4096) {
        int i = b * 1024 + tid * 4;
        float4 v = *(const float4*)(hidden + i);
        us4 o = {bf16r(v.x), bf16r(v.y), bf16r(v.z), bf16r(v.w)};
        *(us4*)(A1bf + i) = o;
        return;
    }
    if (b < 4352) {
        int i = (b - 4096) * 1024 + tid * 4;
        float4 v = *(const float4*)(tsamp + i);
        us4 o = {bf16r(v.x), bf16r(v.y), bf16r(v.z), bf16r(v.w)};
        *(us4*)(Tbf + i) = o;
        float s = v.x * v.x + v.y * v.y + v.z * v.z + v.w * v.w;
#pragma unroll
        for (int off = 8; off; off >>= 1) s += __shfl_xor(s, off);
        if ((tid & 15) == 0) sq_t[i >> 6] = s;
        return;
    }
    // transpose section: in [Rin][C] f32 -> out [C][Rin] bf16 (R = Rin)
    __shared__ float t[32][65];
    const float* in; ushort* out; int R, C;
    int lb = b - 4352;
    if (lb < 2048)      { in = i0; out = o0; R = 1024; C = 4096; }
    else if (lb < 2176) { in = i1; out = o1; R = 4096; C = 64;   lb -= 2048; }
    else if (lb < 2304) { in = i2; out = o2; R = 64;   C = 4096; lb -= 2176; }
    else                { in = i3; out = o3; R = 4096; C = 1024; lb -= 2304; }
    int bx = (lb % (C / 32)) * 32;   // in-col base
    int by = (lb / (C / 32)) * 64;   // in-row base
    int tx = tid & 31, ty = tid >> 5;   // ty 0..7
#pragma unroll
    for (int i = 0; i < 64; i += 8)
        t[tx][i + ty] = in[(size_t)(by + i + ty) * C + (bx + tx)];
    __syncthreads();
#pragma unroll
    for (int i = 0; i < 32; i += 8) {
        int c = i + ty;
        ushort2 o;
        o.x = bf16r(t[c][2 * tx]);
        o.y = bf16r(t[c][2 * tx + 1]);
        *(ushort2*)(&out[(size_t)(bx + c) * R + by + 2 * tx]) = o;
    }
}

// ---------------- MFMA GEMM (2-barrier structure, kept for GEMM3) ----------
// BM=128, BK=64, LDK=64, XOR swizzle k8^=row&7 on staging + read (0 bank
// conflicts).  BN=64: 4x1 waves of 32x64.
template <int BN, int EPI, bool SWZ>
__global__ __launch_bounds__(256) void k_gemm(
        const ushort* __restrict__ A, const ushort* __restrict__ Bt,
        const float* __restrict__ bias, void* __restrict__ Out,
        float* __restrict__ Out2, int M, int N, int K, int KC) {
    constexpr int BM = 128, BK = 64;
    constexpr int WAVES_N = BN / 64;
    constexpr int WAVES_M = 4 / WAVES_N;
    constexpr int WM = BM / WAVES_M;
    constexpr int MT = WM / 16;
    constexpr int NT = 4;
    constexpr int CA = BM / 32, CB = BN / 32;

    __shared__ ushort sA[BM * 64];
    __shared__ ushort sB[BN * 64];

    const int tid  = threadIdx.x;
    const int wave = tid >> 6, lane = tid & 63;
    const int wm = wave / WAVES_N, wn = wave % WAVES_N;
    int bx = blockIdx.x, by = blockIdx.y;
    if constexpr (SWZ) {
        int lin = blockIdx.x + gridDim.x * blockIdx.y;
        by = lin % gridDim.y;
        bx = lin / gridDim.y;
    }
    const int m0 = by * BM, n0 = bx * BN;
    const int lrow = lane & 15, lq = lane >> 4;
    const int srow8 = lane >> 3;
    const int sk8   = lane & 7;
    const int kbeg = blockIdx.z * KC;

    const ushort* pA[CA]; unsigned lA[CA];
#pragma unroll
    for (int j = 0; j < CA; ++j) {
        int c = wave * CA + j;
        int r = c * 8 + srow8;
        pA[j] = &A[(size_t)(m0 + r) * K + kbeg + ((sk8 ^ (r & 7)) * 8)];
        lA[j] = c * 512;
    }
    const ushort* pB[CB]; unsigned lB[CB];
#pragma unroll
    for (int j = 0; j < CB; ++j) {
        int c = wave * CB + j;
        int r = c * 8 + srow8;
        pB[j] = &Bt[(size_t)(n0 + r) * K + kbeg + ((sk8 ^ (r & 7)) * 8)];
        lB[j] = c * 512;
    }
    unsigned aoff[2][MT], boff[2][NT];
#pragma unroll
    for (int h = 0; h < 2; ++h) {
#pragma unroll
        for (int mt = 0; mt < MT; ++mt) {
            int r = wm * WM + mt * 16 + lrow;
            aoff[h][mt] = r * 64 + (((h * 4 + lq) ^ (r & 7)) * 8);
        }
#pragma unroll
        for (int nt = 0; nt < NT; ++nt) {
            int r = wn * 64 + nt * 16 + lrow;
            boff[h][nt] = r * 64 + (((h * 4 + lq) ^ (r & 7)) * 8);
        }
    }

    float4a acc[MT][NT];
#pragma unroll
    for (int mt = 0; mt < MT; ++mt)
#pragma unroll
        for (int nt = 0; nt < NT; ++nt)
            acc[mt][nt] = (float4a){0.f, 0.f, 0.f, 0.f};

    for (int k0 = 0; k0 < KC; k0 += BK) {
#pragma unroll
        for (int j = 0; j < CA; ++j) {
            gld_lds16(pA[j], &sA[lA[j]]);
            pA[j] += BK;
        }
#pragma unroll
        for (int j = 0; j < CB; ++j) {
            gld_lds16(pB[j], &sB[lB[j]]);
            pB[j] += BK;
        }
        __syncthreads();
#pragma unroll
        for (int h = 0; h < 2; ++h) {
            short8 af[MT], bfr[NT];
#pragma unroll
            for (int mt = 0; mt < MT; ++mt)
                af[mt] = *(short8*)(&sA[aoff[h][mt]]);
#pragma unroll
            for (int nt = 0; nt < NT; ++nt)
                bfr[nt] = *(short8*)(&sB[boff[h][nt]]);
#pragma unroll
            for (int mt = 0; mt < MT; ++mt)
#pragma unroll
                for (int nt = 0; nt < NT; ++nt)
                    acc[mt][nt] = __builtin_amdgcn_mfma_f32_16x16x32_bf16(
                        af[mt], bfr[nt], acc[mt][nt], 0, 0, 0);
        }
        __syncthreads();
    }

    float* dstp = nullptr;
    if constexpr (EPI == 2) {
        if (Out2 && blockIdx.z) dstp = Out2;
        else dstp = (float*)Out + (size_t)blockIdx.z * M * N;
    }
#pragma unroll
    for (int mt = 0; mt < MT; ++mt)
#pragma unroll
        for (int nt = 0; nt < NT; ++nt) {
            int col = n0 + wn * 64 + nt * 16 + lrow;
            float bv = 0.f;
            if constexpr (EPI != 2) bv = bias[col];
#pragma unroll
            for (int r = 0; r < 4; ++r) {
                int row = m0 + wm * WM + mt * 16 + lq * 4 + r;
                float v = acc[mt][nt][r] + bv;
                if constexpr (EPI == 0) {
                    ((ushort*)Out)[(size_t)row * N + col] = bf16r(fast_gelu(v));
                } else if constexpr (EPI == 1) {
                    ((float*)Out)[(size_t)row * N + col] = v;
                } else {
                    dstp[(size_t)row * N + col] = v;
                }
            }
        }
}

// ---------------- 3-stage pipelined mb GEMM (GEMM4: 256x128, split-K) ------
// Same min-barrier tile body as R4/R8-mb, but TRIPLE-buffered LDS so the
// boundary wait is counted vmcnt(6), never 0 mid-loop (T4 rule).  Ledger:
//   prologue: stage T0->buf0, T1->buf1; vmcnt(6) => T0 resident; barrier.
//   tile t (buf d=t%3): 24 ds_reads from buf d | stage T(t+2)->buf (t+2)%3
//     [buf was last read by tile t-1; reads retired before its barrier]
//     lgkm(8) | MFMA h0 | lgkm(0) | MFMA h1
//     pf2: vmcnt(6) [FIFO => T(t+1)'s 6 stages done] + barrier
//     else pf1: vmcnt(0) + barrier  (one-time, second-to-last tile)
// LDS = 3*(32K+16K) = 144KB, still 1 block/CU.
template <int CX, int CY>
__global__ __launch_bounds__(512, 2) void k_gemm4p3(
        const ushort* __restrict__ A, const ushort* __restrict__ Bt,
        void* __restrict__ Out, float* __restrict__ Out2,
        int M, int N, int K, int KC) {
    constexpr int BM = 256, BN = 128, BK = 64;
    constexpr int AI = 4, BI = 2;
    constexpr int WAVES_N = 2;
    constexpr int WM = 64, MT = 4, NT = 4;

    __shared__ ushort sA[3][BM * 64];   // 3 x 32KB
    __shared__ ushort sB[3][BN * 64];   // 3 x 16KB

    const int tid = threadIdx.x;
    const int wave = tid >> 6, lane = tid & 63;
    const int wm = wave / WAVES_N, wn = wave % WAVES_N;

    const int gx = gridDim.x, gy = gridDim.y;
    const int lin = blockIdx.x + gx * (blockIdx.y + gy * blockIdx.z);
    const int nwg = gx * gy * gridDim.z;
    const int cpx = nwg >> 3;
    const int swz = (lin & 7) * cpx + (lin >> 3);
    const int nz  = gx * gy;
    const int zz  = swz / nz;
    const int rr  = swz % nz;
    const int chunk = rr / (CX * CY);
    const int lcl   = rr % (CX * CY);
    const int ncx   = gx / CX;
    const int bx = (chunk % ncx) * CX + (lcl % CX);
    const int by = (chunk / ncx) * CY + (lcl / CX);

    const int m0 = by * BM, n0 = bx * BN;
    const int lrow = lane & 15, lq = lane >> 4;
    const int kbeg = zz * KC;
    const int nT = KC / BK;

    const int crow = tid >> 3;
    const int ck8  = (tid & 7) ^ (crow & 7);
    const ushort* pAbase = A  + (size_t)(m0 + crow) * K + kbeg + ck8 * 8;
    const ushort* pBbase = Bt + (size_t)(n0 + crow) * K + kbeg + ck8 * 8;

    const int a0  = (wm * WM + lrow) * 64;
    const int b0  = (wn * 64 + lrow) * 64;
    const int sw0 = ((lq) ^ (lrow & 7)) * 8;
    const int sw1 = ((4 + lq) ^ (lrow & 7)) * 8;

    float4a acc[MT][NT];
#pragma unroll
    for (int mt = 0; mt < MT; ++mt)
#pragma unroll
        for (int nt = 0; nt < NT; ++nt)
            acc[mt][nt] = (float4a){0.f, 0.f, 0.f, 0.f};

    // prologue: T0 -> buf0, T1 -> buf1
#pragma unroll
    for (int j = 0; j < AI; ++j)
        gld_lds16(pAbase + (size_t)j * 64 * K, &sA[0][j * 4096 + wave * 512]);
#pragma unroll
    for (int j = 0; j < BI; ++j)
        gld_lds16(pBbase + (size_t)j * 64 * K, &sB[0][j * 4096 + wave * 512]);
    if (nT > 1) {
#pragma unroll
        for (int j = 0; j < AI; ++j)
            gld_lds16(pAbase + (size_t)j * 64 * K + BK,
                      &sA[1][j * 4096 + wave * 512]);
#pragma unroll
        for (int j = 0; j < BI; ++j)
            gld_lds16(pBbase + (size_t)j * 64 * K + BK,
                      &sB[1][j * 4096 + wave * 512]);
        wait_vmcnt<6>();
    } else {
        wait_vmcnt<0>();
    }
    __builtin_amdgcn_s_barrier();
    __builtin_amdgcn_sched_barrier(0);

    for (int t = 0; t < nT; ++t) {
        const int d  = t % 3;
        const int dn = (t + 2) % 3;
        const bool pf1 = (t + 1 < nT), pf2 = (t + 2 < nT);
        const size_t koff2 = (size_t)(t + 2) * BK;

        short8 af0[MT], bfr0[NT], af1[MT], bfr1[NT];
#pragma unroll
        for (int mt = 0; mt < MT; ++mt)
            af0[mt] = *(const short8*)(&sA[d][a0 + mt * 1024 + sw0]);
#pragma unroll
        for (int nt = 0; nt < NT; ++nt)
            bfr0[nt] = *(const short8*)(&sB[d][b0 + nt * 1024 + sw0]);
        __builtin_amdgcn_sched_barrier(0);   // pin order: h0 batch first
#pragma unroll
        for (int mt = 0; mt < MT; ++mt)
            af1[mt] = *(const short8*)(&sA[d][a0 + mt * 1024 + sw1]);
#pragma unroll
        for (int nt = 0; nt < NT; ++nt)
            bfr1[nt] = *(const short8*)(&sB[d][b0 + nt * 1024 + sw1]);
        if (pf2) {                            // stage T(t+2) into freed buffer
#pragma unroll
            for (int j = 0; j < AI; ++j)
                gld_lds16(pAbase + (size_t)j * 64 * K + koff2,
                          &sA[dn][j * 4096 + wave * 512]);
#pragma unroll
            for (int j = 0; j < BI; ++j)
                gld_lds16(pBbase + (size_t)j * 64 * K + koff2,
                          &sB[dn][j * 4096 + wave * 512]);
        }
        wait_lgkmcnt<8>();                    // af0+bfr0 complete
        __builtin_amdgcn_sched_barrier(0);
        __builtin_amdgcn_s_setprio(1);
#pragma unroll
        for (int mt = 0; mt < MT; ++mt)
#pragma unroll
            for (int nt = 0; nt < NT; ++nt)
                acc[mt][nt] = __builtin_amdgcn_mfma_f32_16x16x32_bf16(
                    af0[mt], bfr0[nt], acc[mt][nt], 0, 0, 0);
        __builtin_amdgcn_s_setprio(0);
        wait_lgkmcnt<0>();
        __builtin_amdgcn_sched_barrier(0);
        __builtin_amdgcn_s_setprio(1);
#pragma unroll
        for (int mt = 0; mt < MT; ++mt)
#pragma unroll
            for (int nt = 0; nt < NT; ++nt)
                acc[mt][nt] = __builtin_amdgcn_mfma_f32_16x16x32_bf16(
                    af1[mt], bfr1[nt], acc[mt][nt], 0, 0, 0);
        __builtin_amdgcn_s_setprio(0);
        if (pf2) {                            // counted boundary wait
            wait_vmcnt<6>();
            __builtin_amdgcn_s_barrier();
            __builtin_amdgcn_sched_barrier(0);
        } else if (pf1) {                     // one-time full drain
            wait_vmcnt<0>();
            __builtin_amdgcn_s_barrier();
            __builtin_amdgcn_sched_barrier(0);
        }
    }

    // epilogue: raw f32 split-K partial
    float* dstp;
    if (Out2 && zz) dstp = Out2;
    else dstp = (float*)Out + (size_t)zz * M * N;
#pragma unroll
    for (int mt = 0; mt < MT; ++mt)
#pragma unroll
        for (int nt = 0; nt < NT; ++nt) {
            const int col = n0 + wn * 64 + nt * 16 + lrow;
#pragma unroll
            for (int r = 0; r < 4; ++r) {
                const int row = m0 + wm * WM + mt * 16 + lq * 4 + r;
                dstp[(size_t)row * N + col] = acc[mt][nt][r];
            }
        }
}

// ---------------- fused GEMM1+GEMM2 (R8-verified: 49.3us) ------------------
__global__ __launch_bounds__(512, 2) void k_gemm1f(
        const ushort* __restrict__ A, const ushort* __restrict__ Bt,
        const float* __restrict__ bias, const ushort* __restrict__ W2t,
        float* __restrict__ part, int M, int N, int K) {
    constexpr int BM = 256, BN = 256, BK = 64;
    constexpr int AI = 4, BI = 4;
    constexpr int WAVES_N = 4;
    constexpr int WM = 128;
    constexpr int MT = 8, NT = 4;
    constexpr int CX = 4, CY = 8;

    __shared__ ushort smem[65536];   // main: sA dbuf | sB dbuf ; epi: sH[256][256]

    const int tid = threadIdx.x;
    const int wave = tid >> 6, lane = tid & 63;
    const int wm = wave / WAVES_N, wn = wave % WAVES_N;

    const int gx = gridDim.x, gy = gridDim.y;
    const int lin = blockIdx.x + gx * blockIdx.y;
    const int cpx = (gx * gy) >> 3;
    const int swz = (lin & 7) * cpx + (lin >> 3);
    const int chunk = swz / (CX * CY);
    const int lcl   = swz % (CX * CY);
    const int ncx   = gx / CX;
    const int bx = (chunk % ncx) * CX + (lcl % CX);
    const int by = (chunk / ncx) * CY + (lcl / CX);

    const int m0 = by * BM, n0 = bx * BN;
    const int lrow = lane & 15, lq = lane >> 4;
    const int nT = K / BK;

    const int crow = tid >> 3;
    const int ck8  = (tid & 7) ^ (crow & 7);
    const ushort* pAbase = A  + (size_t)(m0 + crow) * K + ck8 * 8;
    const ushort* pBbase = Bt + (size_t)(n0 + crow) * K + ck8 * 8;

    const int a0  = (wm * WM + lrow) * 64;
    const int b0  = (wn * 64 + lrow) * 64;
    const int sw0 = ((lq) ^ (lrow & 7)) * 8;
    const int sw1 = ((4 + lq) ^ (lrow & 7)) * 8;

    float4a acc[MT][NT];
#pragma unroll
    for (int mt = 0; mt < MT; ++mt)
#pragma unroll
        for (int nt = 0; nt < NT; ++nt)
            acc[mt][nt] = (float4a){0.f, 0.f, 0.f, 0.f};

#pragma unroll
    for (int j = 0; j < AI; ++j)
        gld_lds16(pAbase + (size_t)j * 64 * K, &smem[j * 4096 + wave * 512]);
#pragma unroll
    for (int j = 0; j < BI; ++j)
        gld_lds16(pBbase + (size_t)j * 64 * K,
                  &smem[32768 + j * 4096 + wave * 512]);
    wait_vmcnt<0>();
    __builtin_amdgcn_s_barrier();
    __builtin_amdgcn_sched_barrier(0);

    for (int t = 0; t < nT; ++t) {
        const int d = t & 1;
        const bool pf1 = (t + 1 < nT);
        const size_t koff1 = (size_t)(t + 1) * 64;
        const ushort* sAd = &smem[d * 16384];
        const ushort* sBd = &smem[32768 + d * 16384];

        short8 af0[MT], bfr0[NT], af1[MT], bfr1[NT];
#pragma unroll
        for (int mt = 0; mt < MT; ++mt)
            af0[mt] = *(const short8*)(&sAd[a0 + mt * 1024 + sw0]);
#pragma unroll
        for (int nt = 0; nt < NT; ++nt)
            bfr0[nt] = *(const short8*)(&sBd[b0 + nt * 1024 + sw0]);
        __builtin_amdgcn_sched_barrier(0);
#pragma unroll
        for (int mt = 0; mt < MT; ++mt)
            af1[mt] = *(const short8*)(&sAd[a0 + mt * 1024 + sw1]);
#pragma unroll
        for (int nt = 0; nt < NT; ++nt)
            bfr1[nt] = *(const short8*)(&sBd[b0 + nt * 1024 + sw1]);
        if (pf1) {
#pragma unroll
            for (int j = 0; j < AI; ++j)
                gld_lds16(pAbase + (size_t)j * 64 * K + koff1,
                          &smem[(d ^ 1) * 16384 + j * 4096 + wave * 512]);
#pragma unroll
            for (int j = 0; j < BI; ++j)
                gld_lds16(pBbase + (size_t)j * 64 * K + koff1,
                          &smem[32768 + (d ^ 1) * 16384 + j * 4096 + wave * 512]);
        }
        wait_lgkmcnt<12>();
        __builtin_amdgcn_sched_barrier(0);
        __builtin_amdgcn_s_setprio(1);
#pragma unroll
        for (int mt = 0; mt < MT; ++mt)
#pragma unroll
            for (int nt = 0; nt < NT; ++nt)
                acc[mt][nt] = __builtin_amdgcn_mfma_f32_16x16x32_bf16(
                    af0[mt], bfr0[nt], acc[mt][nt], 0, 0, 0);
        __builtin_amdgcn_s_setprio(0);
        wait_lgkmcnt<0>();
        __builtin_amdgcn_sched_barrier(0);
        __builtin_amdgcn_s_setprio(1);
#pragma unroll
        for (int mt = 0; mt < MT; ++mt)
#pragma unroll
            for (int nt = 0; nt < NT; ++nt)
                acc[mt][nt] = __builtin_amdgcn_mfma_f32_16x16x32_bf16(
                    af1[mt], bfr1[nt], acc[mt][nt], 0, 0, 0);
        __builtin_amdgcn_s_setprio(0);
        if (pf1) {
            wait_vmcnt<0>();
            __builtin_amdgcn_s_barrier();
            __builtin_amdgcn_sched_barrier(0);
        }
    }

    // fused epilogue: gelu -> sH (LDS), then P = sH x W2slice^T
    __syncthreads();
#pragma unroll
    for (int mt = 0; mt < MT; ++mt)
#pragma unroll
        for (int nt = 0; nt < NT; ++nt) {
            const int c = wn * 64 + nt * 16 + lrow;
            const float bv = bias[n0 + c];
            const int s = c >> 3, cl = c & 7;
#pragma unroll
            for (int r_ = 0; r_ < 4; ++r_) {
                const int r = wm * WM + mt * 16 + lq * 4 + r_;
                const int sz = (s & 24) | ((s & 7) ^ (r & 7));
                smem[r * 256 + sz * 8 + cl] =
                    bf16r(fast_gelu(acc[mt][nt][r_] + bv));
            }
        }
    __syncthreads();

    float4a pacc[2][4];
#pragma unroll
    for (int m2 = 0; m2 < 2; ++m2)
#pragma unroll
        for (int n2 = 0; n2 < 4; ++n2)
            pacc[m2][n2] = (float4a){0.f, 0.f, 0.f, 0.f};

    const ushort* gW2 = W2t + n0;
#pragma unroll
    for (int kk = 0; kk < 8; ++kk) {
        short8 af2[2], bf2[4];
#pragma unroll
        for (int m2 = 0; m2 < 2; ++m2) {
            const int r2 = wave * 32 + m2 * 16 + lrow;
            const int s2 = kk * 4 + lq;
            const int sz2 = (s2 & 24) | ((s2 & 7) ^ (r2 & 7));
            af2[m2] = *(const short8*)(&smem[r2 * 256 + sz2 * 8]);
        }
#pragma unroll
        for (int n2 = 0; n2 < 4; ++n2) {
            const int l = n2 * 16 + lrow;
            bf2[n2] = *(const short8*)(&gW2[(size_t)l * 4096 + kk * 32 + lq * 8]);
        }
#pragma unroll
        for (int m2 = 0; m2 < 2; ++m2)
#pragma unroll
            for (int n2 = 0; n2 < 4; ++n2)
                pacc[m2][n2] = __builtin_amdgcn_mfma_f32_16x16x32_bf16(
                    af2[m2], bf2[n2], pacc[m2][n2], 0, 0, 0);
    }

    float* pz = part + (size_t)bx * M * 64;
#pragma unroll
    for (int m2 = 0; m2 < 2; ++m2)
#pragma unroll
        for (int n2 = 0; n2 < 4; ++n2) {
            const int lat = n2 * 16 + lrow;
#pragma unroll
            for (int r_ = 0; r_ < 4; ++r_) {
                const int row = m0 + wave * 32 + m2 * 16 + lq * 4 + r_;
                pz[(size_t)row * 64 + lat] = pacc[m2][n2][r_];
            }
        }
}

// ---------------- fused MMD grams + ticket finalize ------------------------
// blocks 0..527: tt upper-triangle tiles; 528..1055: ll; 1056..2079: tl full.
// Last block (ticket) computes reg_loss (R9-validated pattern).
__global__ __launch_bounds__(256) void k_gram_all(
        const ushort* __restrict__ Tbf, const ushort* __restrict__ Lbf,
        const float* __restrict__ sq_t, const float* __restrict__ sq_l,
        float* __restrict__ accum, float* __restrict__ regout) {
    __shared__ ushort sX[128 * 64];
    __shared__ ushort sY[128 * 64];
    __shared__ float red[4];

    int id = blockIdx.x;
    int pair, tbx, tby; float w;
    if (id < 1056) {
        pair = (id < 528) ? 0 : 1;
        int t = (pair == 0) ? id : id - 528;
        int r = (int)((sqrtf(8.0f * t + 1.0f) - 1.0f) * 0.5f);
        while ((r + 1) * (r + 2) / 2 <= t) ++r;
        while (r * (r + 1) / 2 > t) --r;
        tby = r; tbx = t - r * (r + 1) / 2;
        w = (tbx == tby) ? 1.0f : 2.0f;
    } else {
        pair = 2; int t = id - 1056;
        tbx = t & 31; tby = t >> 5; w = 1.0f;
    }
    const ushort* Xb = (pair == 1) ? Lbf : Tbf;
    const ushort* Yb = (pair == 0) ? Tbf : Lbf;
    const float* sqX = (pair == 1) ? sq_l : sq_t;
    const float* sqY = (pair == 0) ? sq_t : sq_l;

    const int tid  = threadIdx.x;
    const int wave = tid >> 6, lane = tid & 63;
    const int wm = wave >> 1, wn = wave & 1;
    const int bx = tbx * 128, by = tby * 128;
    const int lrow = lane & 15, lq = lane >> 4;
    const int srow8 = lane >> 3, sk8 = lane & 7;

#pragma unroll
    for (int j = 0; j < 4; ++j) {
        int c = wave * 4 + j;
        int r = c * 8 + srow8;
        int kc = (sk8 ^ (r & 7)) * 8;
        gld_lds16(&Xb[(size_t)(bx + r) * 64 + kc], &sX[c * 512]);
        gld_lds16(&Yb[(size_t)(by + r) * 64 + kc], &sY[c * 512]);
    }

    unsigned xoff[2][4], yoff[2][4];
#pragma unroll
    for (int h = 0; h < 2; ++h)
#pragma unroll
        for (int i = 0; i < 4; ++i) {
            int rx = wm * 64 + i * 16 + lrow;
            int ry = wn * 64 + i * 16 + lrow;
            xoff[h][i] = rx * 64 + (((h * 4 + lq) ^ (rx & 7)) * 8);
            yoff[h][i] = ry * 64 + (((h * 4 + lq) ^ (ry & 7)) * 8);
        }
    __syncthreads();

    float4a acc[4][4];
#pragma unroll
    for (int mt = 0; mt < 4; ++mt)
#pragma unroll
        for (int nt = 0; nt < 4; ++nt)
            acc[mt][nt] = (float4a){0.f, 0.f, 0.f, 0.f};

#pragma unroll
    for (int h = 0; h < 2; ++h) {
        short8 xf[4], yf[4];
#pragma unroll
        for (int mt = 0; mt < 4; ++mt)
            xf[mt] = *(short8*)(&sX[xoff[h][mt]]);
#pragma unroll
        for (int nt = 0; nt < 4; ++nt)
            yf[nt] = *(short8*)(&sY[yoff[h][nt]]);
#pragma unroll
        for (int mt = 0; mt < 4; ++mt)
#pragma unroll
            for (int nt = 0; nt < 4; ++nt)
                acc[mt][nt] = __builtin_amdgcn_mfma_f32_16x16x32_bf16(
                    xf[mt], yf[nt], acc[mt][nt], 0, 0, 0);
    }

    float sy[4];
#pragma unroll
    for (int nt = 0; nt < 4; ++nt)
        sy[nt] = sqY[by + wn * 64 + nt * 16 + lrow];
    float s = 0.f;
#pragma unroll
    for (int mt = 0; mt < 4; ++mt)
#pragma unroll
        for (int r = 0; r < 4; ++r) {
            float sx = sqX[bx + wm * 64 + mt * 16 + lq * 4 + r];
#pragma unroll
            for (int nt = 0; nt < 4; ++nt)
                s += __expf((2.0f * acc[mt][nt][r] - sx - sy[nt]) * (1.0f / 4096.0f));
        }
    s *= w;
#pragma unroll
    for (int off = 32; off; off >>= 1) s += __shfl_xor(s, off);
    if ((tid & 63) == 0) red[tid >> 6] = s;
    __syncthreads();
    if (tid == 0) {
        atomicAdd(accum + pair * 8, red[0] + red[1] + red[2] + red[3]);
        __threadfence();
        unsigned prev = atomicAdd((unsigned*)(accum + 24), 1u);
        if (prev == 2079) {   // last block: finalize
            float a0 = atomicAdd(accum + 0, 0.0f);
            float a1 = atomicAdd(accum + 8, 0.0f);
            float a2 = atomicAdd(accum + 16, 0.0f);
            regout[0] = (a0 + a1 - 2.0f * a2) * (64.0f / (4096.0f * 4096.0f));
        }
    }
}

// ---------------- LayerNorm over 64, split-K reduce, + latent sqnorm -------
__global__ __launch_bounds__(256) void k_ln64_red(
        const float* __restrict__ part, int npart,
        const float* __restrict__ bias, const float* __restrict__ g,
        const float* __restrict__ b, float* __restrict__ outf,
        ushort* __restrict__ outb, float* __restrict__ sq_l) {
    int wave = threadIdx.x >> 6, lane = threadIdx.x & 63;
    int row = blockIdx.x * 4 + wave;
    float x = bias[lane];
    for (int s = 0; s < npart; ++s)
        x += part[(size_t)s * 4096 * 64 + row * 64 + lane];
    float s = x;
#pragma unroll
    for (int off = 32; off; off >>= 1) s += __shfl_xor(s, off);
    float mu = s * (1.0f / 64.0f);
    float d = x - mu;
    float v = d * d;
#pragma unroll
    for (int off = 32; off; off >>= 1) v += __shfl_xor(v, off);
    float rs = rsqrtf(v * (1.0f / 64.0f) + 1e-9f);
    float y = d * rs * g[lane] + b[lane];
    outf[row * 64 + lane] = y;
    outb[row * 64 + lane] = bf16r(y);
    float q = y * y;
#pragma unroll
    for (int off = 32; off; off >>= 1) q += __shfl_xor(q, off);
    if (lane == 0) sq_l[row] = q;
}

// ---------------- LayerNorm over 1024 with 2-partial reduce ----------------
// p1 may alias out (read-before-write within the same block/row).
__global__ __launch_bounds__(256) void k_ln1024_red(
        const float* __restrict__ p0, const float* __restrict__ p1,
        const float* __restrict__ bias, const float* __restrict__ g,
        const float* __restrict__ b, float* __restrict__ out) {
    __shared__ float red[4];
    int row = blockIdx.x, tid = threadIdx.x;
    const float4 v0 = *(const float4*)(p0 + (size_t)row * 1024 + tid * 4);
    const float4 v1 = *(const float4*)(p1 + (size_t)row * 1024 + tid * 4);
    const float4 bb = *(const float4*)(bias + tid * 4);
    float4 v;
    v.x = v0.x + v1.x + bb.x;
    v.y = v0.y + v1.y + bb.y;
    v.z = v0.z + v1.z + bb.z;
    v.w = v0.w + v1.w + bb.w;
    float s = v.x + v.y + v.z + v.w;
#pragma unroll
    for (int off = 32; off; off >>= 1) s += __shfl_xor(s, off);
    if ((tid & 63) == 0) red[tid >> 6] = s;
    __syncthreads();
    float mu = (red[0] + red[1] + red[2] + red[3]) * (1.0f / 1024.0f);
    float dx = v.x - mu, dy = v.y - mu, dz = v.z - mu, dw = v.w - mu;
    float q = dx * dx + dy * dy + dz * dz + dw * dw;
#pragma unroll
    for (int off = 32; off; off >>= 1) q += __shfl_xor(q, off);
    __syncthreads();
    if ((tid & 63) == 0) red[tid >> 6] = q;
    __syncthreads();
    float rs = rsqrtf((red[0] + red[1] + red[2] + red[3]) * (1.0f / 1024.0f) + 1e-9f);
    const float4 gv = *(const float4*)(g + tid * 4);
    const float4 bv = *(const float4*)(b + tid * 4);
    float4 o;
    o.x = dx * rs * gv.x + bv.x;
    o.y = dy * rs * gv.y + bv.y;
    o.z = dz * rs * gv.z + bv.z;
    o.w = dw * rs * gv.w + bv.w;
    *(float4*)(out + (size_t)row * 1024 + tid * 4) = o;
}

// ---------------------------------------------------------------------------
extern "C" void kernel_launch(void* const* d_in, const int* in_sizes, int n_in,
                              void* d_out, int out_size, void* d_ws, size_t ws_size,
                              hipStream_t stream) {
    const float* hidden   = (const float*)d_in[0];
    const float* tsamp    = (const float*)d_in[1];
    const float* enc_w1   = (const float*)d_in[2];
    const float* enc_b1   = (const float*)d_in[3];
    const float* enc_w2   = (const float*)d_in[4];
    const float* enc_b2   = (const float*)d_in[5];
    const float* enc_ln_g = (const float*)d_in[6];
    const float* enc_ln_b = (const float*)d_in[7];
    const float* dec_w1   = (const float*)d_in[8];
    const float* dec_b1   = (const float*)d_in[9];
    const float* dec_w2   = (const float*)d_in[10];
    const float* dec_b2   = (const float*)d_in[11];
    const float* dec_ln_g = (const float*)d_in[12];
    const float* dec_ln_b = (const float*)d_in[13];

    float* out      = (float*)d_out;
    float* recon    = out;                 // 4096*1024
    float* latent_f = out + 4194304;       // 4096*64
    float* reg      = out + 4456448;       // scalar

    char* ws = (char*)d_ws;
    const size_t MB = 1024 * 1024;
    ushort* A1bf = (ushort*)(ws + 0);                 // 8MB  hidden bf16 (dead after GEMM1)
    ushort* W1t  = (ushort*)(ws + 8 * MB);            // 8MB  (dead after GEMM1)
    float*  h4p0 = (float*)(ws + 0);                  // 16MB GEMM4 partial z=0 (z=1 -> recon buf)
    ushort* H1bf = (ushort*)(ws + 16 * MB);           // 32MB dec hidden (GEMM3 out)
    float*  part = (float*)(ws + 16 * MB);            // 16MB enc split-16 partials
                                                      //      (in H1bf region; ln64 drains it
                                                      //       before GEMM3 overwrites)
    ushort* W4t  = (ushort*)(ws + 48 * MB);           // 8MB  [1024,4096]
    ushort* W2t  = (ushort*)(ws + 56 * MB);           // 512K [64,4096]
    ushort* W3t  = (ushort*)(ws + 56 * MB + 512 * 1024); // 512K [4096,64]
    ushort* Lbf  = (ushort*)(ws + 57 * MB);           // 512K latent bf16
    float*  sq_t = (float*)(ws + 59 * MB);            // 16KB
    float*  sq_l = (float*)(ws + 59 * MB + 16384);    // 16KB
    float*  acc3 = (float*)(ws + 59 * MB + 32768);    // 3 accumulators + ticket ctr
    ushort* Tbf  = (ushort*)(ws + 59 * MB + 65536);   // 512K tsamp bf16

    // pre-pass: conversions, transposes (64x32 ushort2 tiles), sqnorms, zeroing
    k_pre<<<8704, 256, 0, stream>>>(hidden, A1bf, tsamp, Tbf, sq_t, acc3,
                                    enc_w1, W1t, enc_w2, W2t,
                                    dec_w1, W3t, dec_w2, W4t);

    // encoder: fused GEMM1+GEMM2 (256x256 mb + latent-partial epilogue)
    k_gemm1f<<<dim3(16, 16, 1), 512, 0, stream>>>(
        A1bf, W1t, enc_b1, W2t, part, 4096, 4096, 1024);
    k_ln64_red<<<1024, 256, 0, stream>>>(part, 16, enc_b2, enc_ln_g, enc_ln_b,
                                         latent_f, Lbf, sq_l);

    // MMD grams (+ ticket finalize inside) -- depends only on Tbf/Lbf/sq_*
    k_gram_all<<<2080, 256, 0, stream>>>(Tbf, Lbf, sq_t, sq_l, acc3, reg);

    // decoder: GEMM3 K=64 (write-bound, old structure)
    k_gemm<64, 0, false><<<dim3(64, 32, 1), 256, 0, stream>>>(
        Lbf, W3t, dec_b1, H1bf, nullptr, 4096, 4096, 64, 64);
    // GEMM4: 3-stage pipelined mb (counted vmcnt), split-K=2 -> 256 blocks
    k_gemm4p3<8, 4><<<dim3(8, 16, 2), 512, 0, stream>>>(
        H1bf, W4t, h4p0, recon, 4096, 1024, 4096, 2048);
    k_ln1024_red<<<4096, 256, 0, stream>>>(h4p0, recon, dec_b2, dec_ln_g,
                                           dec_ln_b, recon);
}

// Round 11
// 246.864 us; speedup vs baseline: 3.2719x; 1.1452x over previous
//
#include <hip/hip_runtime.h>
#include <hip/hip_bf16.h>
#include <math.h>

// ---------------------------------------------------------------------------
// MMD-VAE fused pipeline for MI355X (gfx950)
// B=8 S=512 D=1024 DI=4096 DL=64, Nrows = B*S = 4096
// Outputs: recon [4096,1024] f32, latent [4096,64] f32, reg_loss scalar f32
// R11: exact R8 base (best: 260.6us) except k_gram_all writes per-block
// partials (NO contended atomics -- R10 diagnosis: 2080 same-line
// device-scope atomicAdds serialized block retirement, ~45-56us of stall
// with all pipes idle); k_finalize reduces the 2080 partials in one block.
// gemm4p3 (3-stage) refuted again -> GEMM4 back to proven mb.
// ---------------------------------------------------------------------------

typedef __attribute__((ext_vector_type(8))) short short8;    // 8 bf16 = 4 VGPR
typedef __attribute__((ext_vector_type(4))) float float4a;   // MFMA accum
typedef __attribute__((ext_vector_type(4))) unsigned short us4;

__device__ inline ushort bf16r(float x) {
    union { float f; unsigned u; } c; c.f = x;
    unsigned r = (c.u + 0x7fffu + ((c.u >> 16) & 1u)) >> 16;
    return (ushort)r;
}

// async global->LDS, 16B per lane, LDS dst = wave-uniform base + lane*16
__device__ inline void gld_lds16(const void* g, void* l) {
    __builtin_amdgcn_global_load_lds(
        (const __attribute__((address_space(1))) void*)g,
        (__attribute__((address_space(3))) void*)l, 16, 0, 0);
}

template <int N> __device__ inline void wait_vmcnt() {
    if constexpr (N == 0) asm volatile("s_waitcnt vmcnt(0)" ::: "memory");
    else if constexpr (N == 4) asm volatile("s_waitcnt vmcnt(4)" ::: "memory");
    else if constexpr (N == 6) asm volatile("s_waitcnt vmcnt(6)" ::: "memory");
}

template <int N> __device__ inline void wait_lgkmcnt() {
    if constexpr (N == 0) asm volatile("s_waitcnt lgkmcnt(0)" ::: "memory");
    else if constexpr (N == 8) asm volatile("s_waitcnt lgkmcnt(8)" ::: "memory");
    else if constexpr (N == 12) asm volatile("s_waitcnt lgkmcnt(12)" ::: "memory");
}

// tanh-form gelu via sigmoid identity: 0.5v(1+tanh(z)) = v*sigmoid(2z).
// 2z = 1.5957691*v + 0.07135482*v^3.  |err| <~1e-3 (<< bf16 rounding here).
__device__ inline float fast_gelu(float v) {
    float v2 = v * v;
    float u = v * __builtin_fmaf(0.07135481627f, v2, 1.5957691216f);
    u = fminf(u, 30.0f);                       // overflow guard
    float e = __expf(u);
    return v * e * __builtin_amdgcn_rcpf(e + 1.0f);
}

// ---------------- fused pre-pass: conversions + transposes + zeroing -------
__global__ __launch_bounds__(256) void k_pre(
        const float* __restrict__ hidden, ushort* __restrict__ A1bf,
        const float* __restrict__ tsamp, ushort* __restrict__ Tbf,
        float* __restrict__ sq_t, float* __restrict__ acc,
        const float* __restrict__ i0, ushort* __restrict__ o0,
        const float* __restrict__ i1, ushort* __restrict__ o1,
        const float* __restrict__ i2, ushort* __restrict__ o2,
        const float* __restrict__ i3, ushort* __restrict__ o3) {
    int b = blockIdx.x, tid = threadIdx.x;
    if (b < 4096) {
        int i = b * 1024 + tid * 4;
        float4 v = *(const float4*)(hidden + i);
        us4 o = {bf16r(v.x), bf16r(v.y), bf16r(v.z), bf16r(v.w)};
        *(us4*)(A1bf + i) = o;
        return;
    }
    if (b < 4352) {
        int i = (b - 4096) * 1024 + tid * 4;
        float4 v = *(const float4*)(tsamp + i);
        us4 o = {bf16r(v.x), bf16r(v.y), bf16r(v.z), bf16r(v.w)};
        *(us4*)(Tbf + i) = o;
        float s = v.x * v.x + v.y * v.y + v.z * v.z + v.w * v.w;
#pragma unroll
        for (int off = 8; off; off >>= 1) s += __shfl_xor(s, off);
        if ((tid & 15) == 0) sq_t[i >> 6] = s;
        return;
    }
    // transpose section: in [Rin][C] f32 -> out [C][Rin] bf16 (R = Rin)
    __shared__ float t[32][65];
    const float* in; ushort* out; int R, C;
    int lb = b - 4352;
    if (lb < 2048)      { in = i0; out = o0; R = 1024; C = 4096; }
    else if (lb < 2176) { in = i1; out = o1; R = 4096; C = 64;   lb -= 2048; }
    else if (lb < 2304) { in = i2; out = o2; R = 64;   C = 4096; lb -= 2176; }
    else                { in = i3; out = o3; R = 4096; C = 1024; lb -= 2304; }
    int bx = (lb % (C / 32)) * 32;   // in-col base
    int by = (lb / (C / 32)) * 64;   // in-row base
    int tx = tid & 31, ty = tid >> 5;   // ty 0..7
#pragma unroll
    for (int i = 0; i < 64; i += 8)
        t[tx][i + ty] = in[(size_t)(by + i + ty) * C + (bx + tx)];
    __syncthreads();
#pragma unroll
    for (int i = 0; i < 32; i += 8) {
        int c = i + ty;
        ushort2 o;
        o.x = bf16r(t[c][2 * tx]);
        o.y = bf16r(t[c][2 * tx + 1]);
        *(ushort2*)(&out[(size_t)(bx + c) * R + by + 2 * tx]) = o;
    }
}

// ---------------- MFMA GEMM (2-barrier structure, kept for GEMM3) ----------
// BM=128, BK=64, LDK=64, XOR swizzle k8^=row&7 on staging + read (0 bank
// conflicts).  BN=64: 4x1 waves of 32x64.
template <int BN, int EPI, bool SWZ>
__global__ __launch_bounds__(256) void k_gemm(
        const ushort* __restrict__ A, const ushort* __restrict__ Bt,
        const float* __restrict__ bias, void* __restrict__ Out,
        float* __restrict__ Out2, int M, int N, int K, int KC) {
    constexpr int BM = 128, BK = 64;
    constexpr int WAVES_N = BN / 64;
    constexpr int WAVES_M = 4 / WAVES_N;
    constexpr int WM = BM / WAVES_M;
    constexpr int MT = WM / 16;
    constexpr int NT = 4;
    constexpr int CA = BM / 32, CB = BN / 32;

    __shared__ ushort sA[BM * 64];
    __shared__ ushort sB[BN * 64];

    const int tid  = threadIdx.x;
    const int wave = tid >> 6, lane = tid & 63;
    const int wm = wave / WAVES_N, wn = wave % WAVES_N;
    int bx = blockIdx.x, by = blockIdx.y;
    if constexpr (SWZ) {
        int lin = blockIdx.x + gridDim.x * blockIdx.y;
        by = lin % gridDim.y;
        bx = lin / gridDim.y;
    }
    const int m0 = by * BM, n0 = bx * BN;
    const int lrow = lane & 15, lq = lane >> 4;
    const int srow8 = lane >> 3;
    const int sk8   = lane & 7;
    const int kbeg = blockIdx.z * KC;

    const ushort* pA[CA]; unsigned lA[CA];
#pragma unroll
    for (int j = 0; j < CA; ++j) {
        int c = wave * CA + j;
        int r = c * 8 + srow8;
        pA[j] = &A[(size_t)(m0 + r) * K + kbeg + ((sk8 ^ (r & 7)) * 8)];
        lA[j] = c * 512;
    }
    const ushort* pB[CB]; unsigned lB[CB];
#pragma unroll
    for (int j = 0; j < CB; ++j) {
        int c = wave * CB + j;
        int r = c * 8 + srow8;
        pB[j] = &Bt[(size_t)(n0 + r) * K + kbeg + ((sk8 ^ (r & 7)) * 8)];
        lB[j] = c * 512;
    }
    unsigned aoff[2][MT], boff[2][NT];
#pragma unroll
    for (int h = 0; h < 2; ++h) {
#pragma unroll
        for (int mt = 0; mt < MT; ++mt) {
            int r = wm * WM + mt * 16 + lrow;
            aoff[h][mt] = r * 64 + (((h * 4 + lq) ^ (r & 7)) * 8);
        }
#pragma unroll
        for (int nt = 0; nt < NT; ++nt) {
            int r = wn * 64 + nt * 16 + lrow;
            boff[h][nt] = r * 64 + (((h * 4 + lq) ^ (r & 7)) * 8);
        }
    }

    float4a acc[MT][NT];
#pragma unroll
    for (int mt = 0; mt < MT; ++mt)
#pragma unroll
        for (int nt = 0; nt < NT; ++nt)
            acc[mt][nt] = (float4a){0.f, 0.f, 0.f, 0.f};

    for (int k0 = 0; k0 < KC; k0 += BK) {
#pragma unroll
        for (int j = 0; j < CA; ++j) {
            gld_lds16(pA[j], &sA[lA[j]]);
            pA[j] += BK;
        }
#pragma unroll
        for (int j = 0; j < CB; ++j) {
            gld_lds16(pB[j], &sB[lB[j]]);
            pB[j] += BK;
        }
        __syncthreads();
#pragma unroll
        for (int h = 0; h < 2; ++h) {
            short8 af[MT], bfr[NT];
#pragma unroll
            for (int mt = 0; mt < MT; ++mt)
                af[mt] = *(short8*)(&sA[aoff[h][mt]]);
#pragma unroll
            for (int nt = 0; nt < NT; ++nt)
                bfr[nt] = *(short8*)(&sB[boff[h][nt]]);
#pragma unroll
            for (int mt = 0; mt < MT; ++mt)
#pragma unroll
                for (int nt = 0; nt < NT; ++nt)
                    acc[mt][nt] = __builtin_amdgcn_mfma_f32_16x16x32_bf16(
                        af[mt], bfr[nt], acc[mt][nt], 0, 0, 0);
        }
        __syncthreads();
    }

    float* dstp = nullptr;
    if constexpr (EPI == 2) {
        if (Out2 && blockIdx.z) dstp = Out2;
        else dstp = (float*)Out + (size_t)blockIdx.z * M * N;
    }
#pragma unroll
    for (int mt = 0; mt < MT; ++mt)
#pragma unroll
        for (int nt = 0; nt < NT; ++nt) {
            int col = n0 + wn * 64 + nt * 16 + lrow;
            float bv = 0.f;
            if constexpr (EPI != 2) bv = bias[col];
#pragma unroll
            for (int r = 0; r < 4; ++r) {
                int row = m0 + wm * WM + mt * 16 + lq * 4 + r;
                float v = acc[mt][nt][r] + bv;
                if constexpr (EPI == 0) {
                    ((ushort*)Out)[(size_t)row * N + col] = bf16r(fast_gelu(v));
                } else if constexpr (EPI == 1) {
                    ((float*)Out)[(size_t)row * N + col] = v;
                } else {
                    dstp[(size_t)row * N + col] = v;
                }
            }
        }
}

// ---------------- min-barrier 256-row GEMM (R4/R8-proven, for GEMM4) -------
// BM=256, BK=64, 512 threads = 8 waves, double-buffered LDS, XOR-slot
// swizzle.  ONE barrier per K-tile, counted waits, all issues front-loaded.
// R4/R7/R10 verdict: mb = 41.4us; step-pipeline and 3-stage both regressed.
template <int BN, int EPI, int CX, int CY>
__global__ __launch_bounds__(512, 2) void k_gemm256mb(
        const ushort* __restrict__ A, const ushort* __restrict__ Bt,
        const float* __restrict__ bias, void* __restrict__ Out,
        float* __restrict__ Out2, int M, int N, int K, int KC) {
    constexpr int BM = 256, BK = 64;
    constexpr int AI = 4;
    constexpr int BI = BN / 64;
    constexpr int WAVES_N = BN / 64;
    constexpr int WAVES_M = 8 / WAVES_N;
    constexpr int WM = BM / WAVES_M;
    constexpr int MT = WM / 16;
    constexpr int NT = 4;

    __shared__ ushort sA[2][BM * 64];
    __shared__ ushort sB[2][BN * 64];

    const int tid = threadIdx.x;
    const int wave = tid >> 6, lane = tid & 63;
    const int wm = wave / WAVES_N, wn = wave % WAVES_N;

    const int gx = gridDim.x, gy = gridDim.y;
    const int lin = blockIdx.x + gx * (blockIdx.y + gy * blockIdx.z);
    const int nwg = gx * gy * gridDim.z;
    const int cpx = nwg >> 3;
    const int swz = (lin & 7) * cpx + (lin >> 3);
    const int nz  = gx * gy;
    const int zz  = swz / nz;
    const int rr  = swz % nz;
    const int chunk = rr / (CX * CY);
    const int lcl   = rr % (CX * CY);
    const int ncx   = gx / CX;
    const int bx = (chunk % ncx) * CX + (lcl % CX);
    const int by = (chunk / ncx) * CY + (lcl / CX);

    const int m0 = by * BM, n0 = bx * BN;
    const int lrow = lane & 15, lq = lane >> 4;
    const int kbeg = zz * KC;
    const int nT = KC / BK;

    const int crow = tid >> 3;
    const int ck8  = (tid & 7) ^ (crow & 7);
    const ushort* pAbase = A  + (size_t)(m0 + crow) * K + kbeg + ck8 * 8;
    const ushort* pBbase = Bt + (size_t)(n0 + crow) * K + kbeg + ck8 * 8;

    const int a0  = (wm * WM + lrow) * 64;
    const int b0  = (wn * 64 + lrow) * 64;
    const int sw0 = ((lq) ^ (lrow & 7)) * 8;
    const int sw1 = ((4 + lq) ^ (lrow & 7)) * 8;

    float4a acc[MT][NT];
#pragma unroll
    for (int mt = 0; mt < MT; ++mt)
#pragma unroll
        for (int nt = 0; nt < NT; ++nt)
            acc[mt][nt] = (float4a){0.f, 0.f, 0.f, 0.f};

    // prologue: tile 0 -> buf 0
#pragma unroll
    for (int j = 0; j < AI; ++j)
        gld_lds16(pAbase + (size_t)j * 64 * K, &sA[0][j * 4096 + wave * 512]);
#pragma unroll
    for (int j = 0; j < BI; ++j)
        gld_lds16(pBbase + (size_t)j * 64 * K, &sB[0][j * 4096 + wave * 512]);
    wait_vmcnt<0>();
    __builtin_amdgcn_s_barrier();
    __builtin_amdgcn_sched_barrier(0);

    for (int t = 0; t < nT; ++t) {
        const int d = t & 1;
        const bool pf1 = (t + 1 < nT);
        const size_t koff1 = (size_t)(t + 1) * BK;

        short8 af0[MT], bfr0[NT], af1[MT], bfr1[NT];
#pragma unroll
        for (int mt = 0; mt < MT; ++mt)
            af0[mt] = *(const short8*)(&sA[d][a0 + mt * 1024 + sw0]);
#pragma unroll
        for (int nt = 0; nt < NT; ++nt)
            bfr0[nt] = *(const short8*)(&sB[d][b0 + nt * 1024 + sw0]);
        __builtin_amdgcn_sched_barrier(0);   // pin order: h0 batch first
#pragma unroll
        for (int mt = 0; mt < MT; ++mt)
            af1[mt] = *(const short8*)(&sA[d][a0 + mt * 1024 + sw1]);
#pragma unroll
        for (int nt = 0; nt < NT; ++nt)
            bfr1[nt] = *(const short8*)(&sB[d][b0 + nt * 1024 + sw1]);
        if (pf1) {                            // stage t+1 into dead buffer
#pragma unroll
            for (int j = 0; j < AI; ++j)
                gld_lds16(pAbase + (size_t)j * 64 * K + koff1,
                          &sA[d ^ 1][j * 4096 + wave * 512]);
#pragma unroll
            for (int j = 0; j < BI; ++j)
                gld_lds16(pBbase + (size_t)j * 64 * K + koff1,
                          &sB[d ^ 1][j * 4096 + wave * 512]);
        }
        wait_lgkmcnt<MT + 4>();               // af0+bfr0 complete
        __builtin_amdgcn_sched_barrier(0);
        __builtin_amdgcn_s_setprio(1);
#pragma unroll
        for (int mt = 0; mt < MT; ++mt)
#pragma unroll
            for (int nt = 0; nt < NT; ++nt)
                acc[mt][nt] = __builtin_amdgcn_mfma_f32_16x16x32_bf16(
                    af0[mt], bfr0[nt], acc[mt][nt], 0, 0, 0);
        __builtin_amdgcn_s_setprio(0);
        wait_lgkmcnt<0>();                    // af1+bfr1 complete
        __builtin_amdgcn_sched_barrier(0);
        __builtin_amdgcn_s_setprio(1);
#pragma unroll
        for (int mt = 0; mt < MT; ++mt)
#pragma unroll
            for (int nt = 0; nt < NT; ++nt)
                acc[mt][nt] = __builtin_amdgcn_mfma_f32_16x16x32_bf16(
                    af1[mt], bfr1[nt], acc[mt][nt], 0, 0, 0);
        __builtin_amdgcn_s_setprio(0);
        if (pf1) {                            // boundary: the only barrier
            wait_vmcnt<0>();
            __builtin_amdgcn_s_barrier();
            __builtin_amdgcn_sched_barrier(0);
        }
    }

    // epilogue
    float* dstp = nullptr;
    if constexpr (EPI == 2) {
        if (Out2 && zz) dstp = Out2;
        else dstp = (float*)Out + (size_t)zz * M * N;
    }
#pragma unroll
    for (int mt = 0; mt < MT; ++mt)
#pragma unroll
        for (int nt = 0; nt < NT; ++nt) {
            const int col = n0 + wn * 64 + nt * 16 + lrow;
            float bv = 0.f;
            if constexpr (EPI == 0) bv = bias[col];
#pragma unroll
            for (int r = 0; r < 4; ++r) {
                const int row = m0 + wm * WM + mt * 16 + lq * 4 + r;
                float v = acc[mt][nt][r] + bv;
                if constexpr (EPI == 0)
                    ((ushort*)Out)[(size_t)row * N + col] = bf16r(fast_gelu(v));
                else
                    dstp[(size_t)row * N + col] = v;
            }
        }
}

// ---------------- fused GEMM1+GEMM2 (R8-verified: 49.3us) ------------------
__global__ __launch_bounds__(512, 2) void k_gemm1f(
        const ushort* __restrict__ A, const ushort* __restrict__ Bt,
        const float* __restrict__ bias, const ushort* __restrict__ W2t,
        float* __restrict__ part, int M, int N, int K) {
    constexpr int BM = 256, BN = 256, BK = 64;
    constexpr int AI = 4, BI = 4;
    constexpr int WAVES_N = 4;
    constexpr int WM = 128;
    constexpr int MT = 8, NT = 4;
    constexpr int CX = 4, CY = 8;

    __shared__ ushort smem[65536];   // main: sA dbuf | sB dbuf ; epi: sH[256][256]

    const int tid = threadIdx.x;
    const int wave = tid >> 6, lane = tid & 63;
    const int wm = wave / WAVES_N, wn = wave % WAVES_N;

    const int gx = gridDim.x, gy = gridDim.y;
    const int lin = blockIdx.x + gx * blockIdx.y;
    const int cpx = (gx * gy) >> 3;
    const int swz = (lin & 7) * cpx + (lin >> 3);
    const int chunk = swz / (CX * CY);
    const int lcl   = swz % (CX * CY);
    const int ncx   = gx / CX;
    const int bx = (chunk % ncx) * CX + (lcl % CX);
    const int by = (chunk / ncx) * CY + (lcl / CX);

    const int m0 = by * BM, n0 = bx * BN;
    const int lrow = lane & 15, lq = lane >> 4;
    const int nT = K / BK;

    const int crow = tid >> 3;
    const int ck8  = (tid & 7) ^ (crow & 7);
    const ushort* pAbase = A  + (size_t)(m0 + crow) * K + ck8 * 8;
    const ushort* pBbase = Bt + (size_t)(n0 + crow) * K + ck8 * 8;

    const int a0  = (wm * WM + lrow) * 64;
    const int b0  = (wn * 64 + lrow) * 64;
    const int sw0 = ((lq) ^ (lrow & 7)) * 8;
    const int sw1 = ((4 + lq) ^ (lrow & 7)) * 8;

    float4a acc[MT][NT];
#pragma unroll
    for (int mt = 0; mt < MT; ++mt)
#pragma unroll
        for (int nt = 0; nt < NT; ++nt)
            acc[mt][nt] = (float4a){0.f, 0.f, 0.f, 0.f};

#pragma unroll
    for (int j = 0; j < AI; ++j)
        gld_lds16(pAbase + (size_t)j * 64 * K, &smem[j * 4096 + wave * 512]);
#pragma unroll
    for (int j = 0; j < BI; ++j)
        gld_lds16(pBbase + (size_t)j * 64 * K,
                  &smem[32768 + j * 4096 + wave * 512]);
    wait_vmcnt<0>();
    __builtin_amdgcn_s_barrier();
    __builtin_amdgcn_sched_barrier(0);

    for (int t = 0; t < nT; ++t) {
        const int d = t & 1;
        const bool pf1 = (t + 1 < nT);
        const size_t koff1 = (size_t)(t + 1) * 64;
        const ushort* sAd = &smem[d * 16384];
        const ushort* sBd = &smem[32768 + d * 16384];

        short8 af0[MT], bfr0[NT], af1[MT], bfr1[NT];
#pragma unroll
        for (int mt = 0; mt < MT; ++mt)
            af0[mt] = *(const short8*)(&sAd[a0 + mt * 1024 + sw0]);
#pragma unroll
        for (int nt = 0; nt < NT; ++nt)
            bfr0[nt] = *(const short8*)(&sBd[b0 + nt * 1024 + sw0]);
        __builtin_amdgcn_sched_barrier(0);
#pragma unroll
        for (int mt = 0; mt < MT; ++mt)
            af1[mt] = *(const short8*)(&sAd[a0 + mt * 1024 + sw1]);
#pragma unroll
        for (int nt = 0; nt < NT; ++nt)
            bfr1[nt] = *(const short8*)(&sBd[b0 + nt * 1024 + sw1]);
        if (pf1) {
#pragma unroll
            for (int j = 0; j < AI; ++j)
                gld_lds16(pAbase + (size_t)j * 64 * K + koff1,
                          &smem[(d ^ 1) * 16384 + j * 4096 + wave * 512]);
#pragma unroll
            for (int j = 0; j < BI; ++j)
                gld_lds16(pBbase + (size_t)j * 64 * K + koff1,
                          &smem[32768 + (d ^ 1) * 16384 + j * 4096 + wave * 512]);
        }
        wait_lgkmcnt<12>();
        __builtin_amdgcn_sched_barrier(0);
        __builtin_amdgcn_s_setprio(1);
#pragma unroll
        for (int mt = 0; mt < MT; ++mt)
#pragma unroll
            for (int nt = 0; nt < NT; ++nt)
                acc[mt][nt] = __builtin_amdgcn_mfma_f32_16x16x32_bf16(
                    af0[mt], bfr0[nt], acc[mt][nt], 0, 0, 0);
        __builtin_amdgcn_s_setprio(0);
        wait_lgkmcnt<0>();
        __builtin_amdgcn_sched_barrier(0);
        __builtin_amdgcn_s_setprio(1);
#pragma unroll
        for (int mt = 0; mt < MT; ++mt)
#pragma unroll
            for (int nt = 0; nt < NT; ++nt)
                acc[mt][nt] = __builtin_amdgcn_mfma_f32_16x16x32_bf16(
                    af1[mt], bfr1[nt], acc[mt][nt], 0, 0, 0);
        __builtin_amdgcn_s_setprio(0);
        if (pf1) {
            wait_vmcnt<0>();
            __builtin_amdgcn_s_barrier();
            __builtin_amdgcn_sched_barrier(0);
        }
    }

    // fused epilogue: gelu -> sH (LDS), then P = sH x W2slice^T
    __syncthreads();
#pragma unroll
    for (int mt = 0; mt < MT; ++mt)
#pragma unroll
        for (int nt = 0; nt < NT; ++nt) {
            const int c = wn * 64 + nt * 16 + lrow;
            const float bv = bias[n0 + c];
            const int s = c >> 3, cl = c & 7;
#pragma unroll
            for (int r_ = 0; r_ < 4; ++r_) {
                const int r = wm * WM + mt * 16 + lq * 4 + r_;
                const int sz = (s & 24) | ((s & 7) ^ (r & 7));
                smem[r * 256 + sz * 8 + cl] =
                    bf16r(fast_gelu(acc[mt][nt][r_] + bv));
            }
        }
    __syncthreads();

    float4a pacc[2][4];
#pragma unroll
    for (int m2 = 0; m2 < 2; ++m2)
#pragma unroll
        for (int n2 = 0; n2 < 4; ++n2)
            pacc[m2][n2] = (float4a){0.f, 0.f, 0.f, 0.f};

    const ushort* gW2 = W2t + n0;
#pragma unroll
    for (int kk = 0; kk < 8; ++kk) {
        short8 af2[2], bf2[4];
#pragma unroll
        for (int m2 = 0; m2 < 2; ++m2) {
            const int r2 = wave * 32 + m2 * 16 + lrow;
            const int s2 = kk * 4 + lq;
            const int sz2 = (s2 & 24) | ((s2 & 7) ^ (r2 & 7));
            af2[m2] = *(const short8*)(&smem[r2 * 256 + sz2 * 8]);
        }
#pragma unroll
        for (int n2 = 0; n2 < 4; ++n2) {
            const int l = n2 * 16 + lrow;
            bf2[n2] = *(const short8*)(&gW2[(size_t)l * 4096 + kk * 32 + lq * 8]);
        }
#pragma unroll
        for (int m2 = 0; m2 < 2; ++m2)
#pragma unroll
            for (int n2 = 0; n2 < 4; ++n2)
                pacc[m2][n2] = __builtin_amdgcn_mfma_f32_16x16x32_bf16(
                    af2[m2], bf2[n2], pacc[m2][n2], 0, 0, 0);
    }

    float* pz = part + (size_t)bx * M * 64;
#pragma unroll
    for (int m2 = 0; m2 < 2; ++m2)
#pragma unroll
        for (int n2 = 0; n2 < 4; ++n2) {
            const int lat = n2 * 16 + lrow;
#pragma unroll
            for (int r_ = 0; r_ < 4; ++r_) {
                const int row = m0 + wave * 32 + m2 * 16 + lq * 4 + r_;
                pz[(size_t)row * 64 + lat] = pacc[m2][n2][r_];
            }
        }
}

// ---------------- fused MMD grams (per-block partials, NO atomics) ---------
// blocks 0..527: tt upper-triangle tiles; 528..1055: ll; 1056..2079: tl full.
// Off-diagonal symmetric tiles weighted 2x; diagonal tiles exact (incl i==j).
// Each block writes its weighted partial to bsum[blockIdx.x]; k_finalize
// range-sums.  (R10 diagnosis: contended same-line atomics serialized block
// retirement -> ~45us of all-pipes-idle stall.)
__global__ __launch_bounds__(256) void k_gram_all(
        const ushort* __restrict__ Tbf, const ushort* __restrict__ Lbf,
        const float* __restrict__ sq_t, const float* __restrict__ sq_l,
        float* __restrict__ bsum) {
    __shared__ ushort sX[128 * 64];
    __shared__ ushort sY[128 * 64];
    __shared__ float red[4];

    int id = blockIdx.x;
    int pair, tbx, tby; float w;
    if (id < 1056) {
        pair = (id < 528) ? 0 : 1;
        int t = (pair == 0) ? id : id - 528;
        int r = (int)((sqrtf(8.0f * t + 1.0f) - 1.0f) * 0.5f);
        while ((r + 1) * (r + 2) / 2 <= t) ++r;
        while (r * (r + 1) / 2 > t) --r;
        tby = r; tbx = t - r * (r + 1) / 2;
        w = (tbx == tby) ? 1.0f : 2.0f;
    } else {
        pair = 2; int t = id - 1056;
        tbx = t & 31; tby = t >> 5; w = 1.0f;
    }
    const ushort* Xb = (pair == 1) ? Lbf : Tbf;
    const ushort* Yb = (pair == 0) ? Tbf : Lbf;
    const float* sqX = (pair == 1) ? sq_l : sq_t;
    const float* sqY = (pair == 0) ? sq_t : sq_l;

    const int tid  = threadIdx.x;
    const int wave = tid >> 6, lane = tid & 63;
    const int wm = wave >> 1, wn = wave & 1;
    const int bx = tbx * 128, by = tby * 128;
    const int lrow = lane & 15, lq = lane >> 4;
    const int srow8 = lane >> 3, sk8 = lane & 7;

#pragma unroll
    for (int j = 0; j < 4; ++j) {
        int c = wave * 4 + j;
        int r = c * 8 + srow8;
        int kc = (sk8 ^ (r & 7)) * 8;
        gld_lds16(&Xb[(size_t)(bx + r) * 64 + kc], &sX[c * 512]);
        gld_lds16(&Yb[(size_t)(by + r) * 64 + kc], &sY[c * 512]);
    }

    unsigned xoff[2][4], yoff[2][4];
#pragma unroll
    for (int h = 0; h < 2; ++h)
#pragma unroll
        for (int i = 0; i < 4; ++i) {
            int rx = wm * 64 + i * 16 + lrow;
            int ry = wn * 64 + i * 16 + lrow;
            xoff[h][i] = rx * 64 + (((h * 4 + lq) ^ (rx & 7)) * 8);
            yoff[h][i] = ry * 64 + (((h * 4 + lq) ^ (ry & 7)) * 8);
        }
    __syncthreads();

    float4a acc[4][4];
#pragma unroll
    for (int mt = 0; mt < 4; ++mt)
#pragma unroll
        for (int nt = 0; nt < 4; ++nt)
            acc[mt][nt] = (float4a){0.f, 0.f, 0.f, 0.f};

#pragma unroll
    for (int h = 0; h < 2; ++h) {
        short8 xf[4], yf[4];
#pragma unroll
        for (int mt = 0; mt < 4; ++mt)
            xf[mt] = *(short8*)(&sX[xoff[h][mt]]);
#pragma unroll
        for (int nt = 0; nt < 4; ++nt)
            yf[nt] = *(short8*)(&sY[yoff[h][nt]]);
#pragma unroll
        for (int mt = 0; mt < 4; ++mt)
#pragma unroll
            for (int nt = 0; nt < 4; ++nt)
                acc[mt][nt] = __builtin_amdgcn_mfma_f32_16x16x32_bf16(
                    xf[mt], yf[nt], acc[mt][nt], 0, 0, 0);
    }

    float sy[4];
#pragma unroll
    for (int nt = 0; nt < 4; ++nt)
        sy[nt] = sqY[by + wn * 64 + nt * 16 + lrow];
    float s = 0.f;
#pragma unroll
    for (int mt = 0; mt < 4; ++mt)
#pragma unroll
        for (int r = 0; r < 4; ++r) {
            float sx = sqX[bx + wm * 64 + mt * 16 + lq * 4 + r];
#pragma unroll
            for (int nt = 0; nt < 4; ++nt)
                s += __expf((2.0f * acc[mt][nt][r] - sx - sy[nt]) * (1.0f / 4096.0f));
        }
    s *= w;
#pragma unroll
    for (int off = 32; off; off >>= 1) s += __shfl_xor(s, off);
    if ((tid & 63) == 0) red[tid >> 6] = s;
    __syncthreads();
    if (tid == 0) bsum[id] = red[0] + red[1] + red[2] + red[3];
}

// ---------------- finalize: range-sum the 2080 gram partials ---------------
__global__ __launch_bounds__(256) void k_finalize(
        const float* __restrict__ bsum, float* __restrict__ out) {
    __shared__ float red[12];
    int tid = threadIdx.x;
    float s0 = 0.f, s1 = 0.f, s2 = 0.f;
    for (int i = tid; i < 2080; i += 256) {
        float v = bsum[i];
        if (i < 528) s0 += v;
        else if (i < 1056) s1 += v;
        else s2 += v;
    }
#pragma unroll
    for (int off = 32; off; off >>= 1) {
        s0 += __shfl_xor(s0, off);
        s1 += __shfl_xor(s1, off);
        s2 += __shfl_xor(s2, off);
    }
    if ((tid & 63) == 0) {
        int w = tid >> 6;
        red[w] = s0; red[4 + w] = s1; red[8 + w] = s2;
    }
    __syncthreads();
    if (tid == 0) {
        float a0 = red[0] + red[1] + red[2] + red[3];
        float a1 = red[4] + red[5] + red[6] + red[7];
        float a2 = red[8] + red[9] + red[10] + red[11];
        out[0] = (a0 + a1 - 2.0f * a2) * (64.0f / (4096.0f * 4096.0f));
    }
}

// ---------------- LayerNorm over 64, split-K reduce, + latent sqnorm -------
__global__ __launch_bounds__(256) void k_ln64_red(
        const float* __restrict__ part, int npart,
        const float* __restrict__ bias, const float* __restrict__ g,
        const float* __restrict__ b, float* __restrict__ outf,
        ushort* __restrict__ outb, float* __restrict__ sq_l) {
    int wave = threadIdx.x >> 6, lane = threadIdx.x & 63;
    int row = blockIdx.x * 4 + wave;
    float x = bias[lane];
    for (int s = 0; s < npart; ++s)
        x += part[(size_t)s * 4096 * 64 + row * 64 + lane];
    float s = x;
#pragma unroll
    for (int off = 32; off; off >>= 1) s += __shfl_xor(s, off);
    float mu = s * (1.0f / 64.0f);
    float d = x - mu;
    float v = d * d;
#pragma unroll
    for (int off = 32; off; off >>= 1) v += __shfl_xor(v, off);
    float rs = rsqrtf(v * (1.0f / 64.0f) + 1e-9f);
    float y = d * rs * g[lane] + b[lane];
    outf[row * 64 + lane] = y;
    outb[row * 64 + lane] = bf16r(y);
    float q = y * y;
#pragma unroll
    for (int off = 32; off; off >>= 1) q += __shfl_xor(q, off);
    if (lane == 0) sq_l[row] = q;
}

// ---------------- LayerNorm over 1024 with 2-partial reduce ----------------
// p1 may alias out (read-before-write within the same block/row).
__global__ __launch_bounds__(256) void k_ln1024_red(
        const float* __restrict__ p0, const float* __restrict__ p1,
        const float* __restrict__ bias, const float* __restrict__ g,
        const float* __restrict__ b, float* __restrict__ out) {
    __shared__ float red[4];
    int row = blockIdx.x, tid = threadIdx.x;
    const float4 v0 = *(const float4*)(p0 + (size_t)row * 1024 + tid * 4);
    const float4 v1 = *(const float4*)(p1 + (size_t)row * 1024 + tid * 4);
    const float4 bb = *(const float4*)(bias + tid * 4);
    float4 v;
    v.x = v0.x + v1.x + bb.x;
    v.y = v0.y + v1.y + bb.y;
    v.z = v0.z + v1.z + bb.z;
    v.w = v0.w + v1.w + bb.w;
    float s = v.x + v.y + v.z + v.w;
#pragma unroll
    for (int off = 32; off; off >>= 1) s += __shfl_xor(s, off);
    if ((tid & 63) == 0) red[tid >> 6] = s;
    __syncthreads();
    float mu = (red[0] + red[1] + red[2] + red[3]) * (1.0f / 1024.0f);
    float dx = v.x - mu, dy = v.y - mu, dz = v.z - mu, dw = v.w - mu;
    float q = dx * dx + dy * dy + dz * dz + dw * dw;
#pragma unroll
    for (int off = 32; off; off >>= 1) q += __shfl_xor(q, off);
    __syncthreads();
    if ((tid & 63) == 0) red[tid >> 6] = q;
    __syncthreads();
    float rs = rsqrtf((red[0] + red[1] + red[2] + red[3]) * (1.0f / 1024.0f) + 1e-9f);
    const float4 gv = *(const float4*)(g + tid * 4);
    const float4 bv = *(const float4*)(b + tid * 4);
    float4 o;
    o.x = dx * rs * gv.x + bv.x;
    o.y = dy * rs * gv.y + bv.y;
    o.z = dz * rs * gv.z + bv.z;
    o.w = dw * rs * gv.w + bv.w;
    *(float4*)(out + (size_t)row * 1024 + tid * 4) = o;
}

// ---------------------------------------------------------------------------
extern "C" void kernel_launch(void* const* d_in, const int* in_sizes, int n_in,
                              void* d_out, int out_size, void* d_ws, size_t ws_size,
                              hipStream_t stream) {
    const float* hidden   = (const float*)d_in[0];
    const float* tsamp    = (const float*)d_in[1];
    const float* enc_w1   = (const float*)d_in[2];
    const float* enc_b1   = (const float*)d_in[3];
    const float* enc_w2   = (const float*)d_in[4];
    const float* enc_b2   = (const float*)d_in[5];
    const float* enc_ln_g = (const float*)d_in[6];
    const float* enc_ln_b = (const float*)d_in[7];
    const float* dec_w1   = (const float*)d_in[8];
    const float* dec_b1   = (const float*)d_in[9];
    const float* dec_w2   = (const float*)d_in[10];
    const float* dec_b2   = (const float*)d_in[11];
    const float* dec_ln_g = (const float*)d_in[12];
    const float* dec_ln_b = (const float*)d_in[13];

    float* out      = (float*)d_out;
    float* recon    = out;                 // 4096*1024
    float* latent_f = out + 4194304;       // 4096*64
    float* reg      = out + 4456448;       // scalar

    char* ws = (char*)d_ws;
    const size_t MB = 1024 * 1024;
    ushort* A1bf = (ushort*)(ws + 0);                 // 8MB  hidden bf16 (dead after GEMM1)
    ushort* W1t  = (ushort*)(ws + 8 * MB);            // 8MB  (dead after GEMM1)
    float*  h4p0 = (float*)(ws + 0);                  // 16MB GEMM4 partial z=0 (z=1 -> recon buf)
    ushort* H1bf = (ushort*)(ws + 16 * MB);           // 32MB dec hidden (GEMM3 out)
    float*  part = (float*)(ws + 16 * MB);            // 16MB enc split-16 partials
                                                      //      (in H1bf region; ln64 drains it
                                                      //       before GEMM3 overwrites)
    ushort* W4t  = (ushort*)(ws + 48 * MB);           // 8MB  [1024,4096]
    ushort* W2t  = (ushort*)(ws + 56 * MB);           // 512K [64,4096]
    ushort* W3t  = (ushort*)(ws + 56 * MB + 512 * 1024); // 512K [4096,64]
    ushort* Lbf  = (ushort*)(ws + 57 * MB);           // 512K latent bf16
    float*  sq_t = (float*)(ws + 59 * MB);            // 16KB
    float*  sq_l = (float*)(ws + 59 * MB + 16384);    // 16KB
    float*  bsum = (float*)(ws + 59 * MB + 32768);    // 8.3KB gram per-block partials
    ushort* Tbf  = (ushort*)(ws + 59 * MB + 65536);   // 512K tsamp bf16

    // pre-pass: conversions, transposes (64x32 ushort2 tiles), sqnorms
    k_pre<<<8704, 256, 0, stream>>>(hidden, A1bf, tsamp, Tbf, sq_t, nullptr,
                                    enc_w1, W1t, enc_w2, W2t,
                                    dec_w1, W3t, dec_w2, W4t);

    // encoder: fused GEMM1+GEMM2 (256x256 mb + latent-partial epilogue)
    k_gemm1f<<<dim3(16, 16, 1), 512, 0, stream>>>(
        A1bf, W1t, enc_b1, W2t, part, 4096, 4096, 1024);
    k_ln64_red<<<1024, 256, 0, stream>>>(part, 16, enc_b2, enc_ln_g, enc_ln_b,
                                         latent_f, Lbf, sq_l);

    // decoder: GEMM3 K=64 (write-bound, old structure)
    k_gemm<64, 0, false><<<dim3(64, 32, 1), 256, 0, stream>>>(
        Lbf, W3t, dec_b1, H1bf, nullptr, 4096, 4096, 64, 64);
    // GEMM4: min-barrier 256x128 (R4/R8-proven 41.4us), split-K=2 -> 256 blocks
    k_gemm256mb<128, 2, 8, 4><<<dim3(8, 16, 2), 512, 0, stream>>>(
        H1bf, W4t, nullptr, h4p0, recon, 4096, 1024, 4096, 2048);
    k_ln1024_red<<<4096, 256, 0, stream>>>(h4p0, recon, dec_b2, dec_ln_g,
                                           dec_ln_b, recon);

    // MMD: grams (per-block partials, no atomics), then one-block finalize
    k_gram_all<<<2080, 256, 0, stream>>>(Tbf, Lbf, sq_t, sq_l, bsum);
    k_finalize<<<1, 256, 0, stream>>>(bsum, reg);
}